// Round 12
// baseline (578.991 us; speedup 1.0000x reference)
//
#include <hip/hip_runtime.h>
#include <hip/hip_bf16.h>

#define NC 100000
#define NP 200000
#define NE 1000000
#define NN2 (2 * NP)      // combined dst-node space (pp then cp)
#define NBUK 391          // ceil(NN2/1024)
#define ECHUNK 8192
#define NBLK_E 245        // ceil(2*NE/8192)
#define NBLK_C 1563       // ceil(NC/64)

typedef unsigned short u16;
typedef unsigned int u32;
typedef unsigned long long u64;
typedef __attribute__((ext_vector_type(8))) short short8v;  // 8 bf16 (4 VGPRs)
typedef __attribute__((ext_vector_type(4))) float f32x4;

__device__ __forceinline__ float bf2f(u16 v) {
    union { u32 u; float f; } c; c.u = ((u32)v) << 16; return c.f;
}
__device__ __forceinline__ u16 f2bf(float f) {
    union { float f; u32 u; } c; c.f = f;
    u32 u = c.u;
    return (u16)((u + 0x7FFFu + ((u >> 16) & 1u)) >> 16); // RNE
}
__device__ __forceinline__ u32 pack2(float lo, float hi) {
    return (u32)f2bf(lo) | ((u32)f2bf(hi) << 16);
}
__device__ __forceinline__ float tanh_fast(float x) {
    return 1.f - 2.f / (__expf(2.f * x) + 1.f);
}
__device__ __forceinline__ short8v mk8(u32 a, u32 b, u32 c, u32 d) {
    union { u32 u[4]; short8v v; } t; t.u[0] = a; t.u[1] = b; t.u[2] = c; t.u[3] = d; return t.v;
}

// ===== wconv: one-time f32 -> bf16 transposed weight tables =====
// WcT/WpT: [n=128][k=64]; WkT/W1T: [n=128][k=128]; W2T: [n=64][k=128]
__global__ __launch_bounds__(256) void wconv(
    const float* __restrict__ Wc, const float* __restrict__ Wp, const float* __restrict__ Wk,
    const float* __restrict__ W1, const float* __restrict__ W2,
    u16* __restrict__ WcT, u16* __restrict__ WpT, u16* __restrict__ WkT,
    u16* __restrict__ W1T, u16* __restrict__ W2T)
{
    int i = blockIdx.x * 256 + threadIdx.x;
    if (i < 8192)       { int n = i >> 6, k = i & 63;                 WcT[i] = f2bf(Wc[k * 128 + n]); }
    else if (i < 16384) { int j = i - 8192;  int n = j >> 6, k = j & 63;   WpT[j] = f2bf(Wp[k * 128 + n]); }
    else if (i < 32768) { int j = i - 16384; int n = j >> 7, k = j & 127;  WkT[j] = f2bf(Wk[k * 128 + n]); }
    else if (i < 49152) { int j = i - 32768; int n = j >> 7, k = j & 127;  W1T[j] = f2bf(W1[k * 128 + n]); }
    else if (i < 57344) { int j = i - 49152; int n = j >> 7, k = j & 127;  W2T[j] = f2bf(W2[k * 64 + n]); }
}

// ========== proj (both types), A+B direct-from-global, + fused logits; idle blocks run bhist ==========
__global__ __launch_bounds__(256) void proj_both(
    const float* __restrict__ x_c, const u16* __restrict__ WcT, const float* __restrict__ b_c,
    const float* __restrict__ x_p, const u16* __restrict__ WpT, const float* __restrict__ b_p,
    u16* __restrict__ out_c, u16* __restrict__ out_p,
    const float* __restrict__ a_cp_s,
    const float* __restrict__ a_cp_d, const float* __restrict__ a_pp_s,
    const float* __restrict__ a_pp_d,
    float* __restrict__ al_c, float* __restrict__ al_dcp,
    float* __restrict__ al_spp, float* __restrict__ al_dpp,
    const int* __restrict__ dpp, const int* __restrict__ dcp, int* __restrict__ bcnt)
{
    __shared__ alignas(16) char smem[18944];
    u16* hTile = (u16*)smem;             // 64*136*2 = 17408
    float* aV  = (float*)(smem + 17408); // 3*128*4  =  1536
    int* hh    = (int*)smem;             // bhist branch only
    int t = threadIdx.x;
    int py = blockIdx.y;
    int bx = blockIdx.x;

    if (py == 0 && bx >= NBLK_C) {
        int bb = bx - NBLK_C;
        if (bb >= NBLK_E) return;
        for (int i = t; i < NBUK; i += 256) hh[i] = 0;
        __syncthreads();
        int base = bb * ECHUNK;
        int lim = min(ECHUNK, 2 * NE - base);
        for (int i = t; i < lim; i += 256) {
            int e = base + i;
            int d2 = (e < NE) ? dpp[e] : NP + dcp[e - NE];
            atomicAdd(&hh[d2 >> 10], 1);
        }
        __syncthreads();
        for (int i = t; i < NBUK; i += 256) if (hh[i]) atomicAdd(&bcnt[i], hh[i]);
        return;
    }

    const float* x; const u16* WT; const float* b; u16* h; int N;
    if (py == 0) { x = x_c; WT = WcT; b = b_c; h = out_c; N = NC; }
    else         { x = x_p; WT = WpT; b = b_p; h = out_p; N = NP; }
    size_t row0 = (size_t)bx * 64;
    if (t < 128) {
        aV[t]       = py ? a_cp_d[t] : a_cp_s[t];
        aV[128 + t] = py ? a_pp_s[t] : 0.f;
        aV[256 + t] = py ? a_pp_d[t] : 0.f;
    }
    int wave = t >> 6, lane = t & 63;
    int fr = lane & 15, fq = lane >> 4;
    size_t arow = row0 + wave * 16 + fr;
    short8v afr[2];
#pragma unroll
    for (int ks = 0; ks < 2; ++ks) {
        if (arow < (size_t)N) {
            const float* xp = x + arow * 64 + ks * 32 + fq * 8;
            float4 v0 = *(const float4*)xp;
            float4 v1 = *(const float4*)(xp + 4);
            afr[ks] = mk8(pack2(v0.x, v0.y), pack2(v0.z, v0.w),
                          pack2(v1.x, v1.y), pack2(v1.z, v1.w));
        } else afr[ks] = mk8(0, 0, 0, 0);
    }
    f32x4 acc[8];
#pragma unroll
    for (int nt = 0; nt < 8; ++nt) { float bb2 = b[nt * 16 + fr]; acc[nt] = (f32x4){bb2, bb2, bb2, bb2}; }
#pragma unroll
    for (int ks = 0; ks < 2; ++ks) {
#pragma unroll
        for (int nt = 0; nt < 8; ++nt) {
            short8v bv = *(const short8v*)(WT + (nt * 16 + fr) * 64 + ks * 32 + fq * 8);
            acc[nt] = __builtin_amdgcn_mfma_f32_16x16x32_bf16(afr[ks], bv, acc[nt], 0, 0, 0);
        }
    }
    size_t rbase = row0 + wave * 16 + fq * 4;
    int lrow0 = wave * 16 + fq * 4;
#pragma unroll
    for (int nt = 0; nt < 8; ++nt) {
        int col = nt * 16 + fr;
#pragma unroll
        for (int rg = 0; rg < 4; ++rg) {
            size_t rr = rbase + rg;
            u16 hv = f2bf(acc[nt][rg]);
            if (rr < (size_t)N) h[rr * 128 + col] = hv;
            hTile[(lrow0 + rg) * 136 + col] = hv;
        }
    }
    __syncthreads();
    int row = t >> 2;
    size_t grow = row0 + row;
    if (grow < (size_t)N) {
#pragma unroll
        for (int hd = t & 3; hd < 8; hd += 4) {
            const u16* hp = &hTile[row * 136 + hd * 16];
            uint4 u0_ = *(const uint4*)hp;
            uint4 u1_ = *(const uint4*)(hp + 8);
            u32 uu[8] = {u0_.x, u0_.y, u0_.z, u0_.w, u1_.x, u1_.y, u1_.z, u1_.w};
            float p0 = 0.f, p1 = 0.f, p2 = 0.f;
#pragma unroll
            for (int j = 0; j < 8; ++j) {
                float lo = bf2f((u16)(uu[j] & 0xFFFFu));
                float hi = bf2f((u16)(uu[j] >> 16));
                int c = hd * 16 + 2 * j;
                p0 += lo * aV[c]       + hi * aV[c + 1];
                p1 += lo * aV[128 + c] + hi * aV[128 + c + 1];
                p2 += lo * aV[256 + c] + hi * aV[256 + c + 1];
            }
            if (py == 0) {
                al_c[grow * 8 + hd] = p0;
            } else {
                al_dcp[grow * 8 + hd] = p0;
                al_spp[grow * 8 + hd] = p1;
                al_dpp[grow * 8 + hd] = p2;
            }
        }
    }
}

// ================= bucketed CSR build =================
__global__ __launch_bounds__(512) void bscan(const int* __restrict__ bcnt, int* __restrict__ bbase,
                                             int* __restrict__ bcur, int* __restrict__ row_ptr)
{
    __shared__ int s[512];
    int t = threadIdx.x;
    int v = (t < NBUK) ? bcnt[t] : 0;
    s[t] = v;
    __syncthreads();
    for (int off = 1; off < 512; off <<= 1) {
        int x = (t >= off) ? s[t - off] : 0;
        __syncthreads();
        s[t] += x;
        __syncthreads();
    }
    if (t < NBUK) { bbase[t] = s[t] - v; bcur[t] = s[t] - v; }
    if (t == 0) { bbase[NBUK] = 2 * NE; row_ptr[NN2] = 2 * NE; }
}

__global__ __launch_bounds__(256) void bplace(
    const int* __restrict__ spp, const int* __restrict__ dpp,
    const int* __restrict__ scp, const int* __restrict__ dcp,
    int* __restrict__ bcur, u64* __restrict__ pairs)
{
    __shared__ int h[NBUK];
    __shared__ int rk[NBUK];
    int t = threadIdx.x;
    for (int i = t; i < NBUK; i += 256) h[i] = 0;
    __syncthreads();
    int base = blockIdx.x * ECHUNK;
    int lim = min(ECHUNK, 2 * NE - base);
    for (int i = t; i < lim; i += 256) {
        int e = base + i;
        int d2 = (e < NE) ? dpp[e] : NP + dcp[e - NE];
        atomicAdd(&h[d2 >> 10], 1);
    }
    __syncthreads();
    for (int i = t; i < NBUK; i += 256) {
        int c = h[i];
        h[i] = c ? atomicAdd(&bcur[i], c) : 0;
        rk[i] = 0;
    }
    __syncthreads();
    for (int i = t; i < lim; i += 256) {
        int e = base + i;
        int d2, src;
        if (e < NE) { d2 = dpp[e];      src = spp[e]; }
        else        { d2 = NP + dcp[e - NE]; src = scp[e - NE]; }
        int b = d2 >> 10;
        int r = atomicAdd(&rk[b], 1);
        pairs[h[b] + r] = ((u64)(u32)d2 << 32) | (u32)src;
    }
}

__global__ __launch_bounds__(256) void bsort(
    const u64* __restrict__ pairs, const int* __restrict__ bbase,
    int* __restrict__ row_ptr, int* __restrict__ perm)
{
    __shared__ int cnt[1024];
    __shared__ int sc[256];
    int b = blockIdx.x, t = threadIdx.x;
    int beg = bbase[b], end = bbase[b + 1];
    for (int i = t; i < 1024; i += 256) cnt[i] = 0;
    __syncthreads();
    for (int i = beg + t; i < end; i += 256) {
        int d2 = (int)(pairs[i] >> 32);
        atomicAdd(&cnt[d2 & 1023], 1);
    }
    __syncthreads();
    int b4 = t * 4;
    int c0 = cnt[b4], c1 = cnt[b4 + 1], c2 = cnt[b4 + 2], c3 = cnt[b4 + 3];
    int s = c0 + c1 + c2 + c3;
    sc[t] = s;
    __syncthreads();
    for (int off = 1; off < 256; off <<= 1) {
        int x = (t >= off) ? sc[t - off] : 0;
        __syncthreads();
        sc[t] += x;
        __syncthreads();
    }
    int run = sc[t] - s;
    int o0 = run, o1 = run + c0, o2 = o1 + c1, o3 = o2 + c2;
    cnt[b4] = o0; cnt[b4 + 1] = o1; cnt[b4 + 2] = o2; cnt[b4 + 3] = o3;
    int gidx = b * 1024 + b4;
    if (gidx     < NN2) row_ptr[gidx]     = beg + o0;
    if (gidx + 1 < NN2) row_ptr[gidx + 1] = beg + o1;
    if (gidx + 2 < NN2) row_ptr[gidx + 2] = beg + o2;
    if (gidx + 3 < NN2) row_ptr[gidx + 3] = beg + o3;
    __syncthreads();
    for (int i = beg + t; i < end; i += 256) {
        u64 p = pairs[i];
        int d2 = (int)(p >> 32);
        int r = atomicAdd(&cnt[d2 & 1023], 1);
        perm[beg + r] = (int)(p & 0xFFFFFFFFull);
    }
}

// ===== gather (round-7 proven): 16 lanes/dst, perm preload + 1-deep pipeline =====
__global__ __launch_bounds__(256) void gather2(
    const int* __restrict__ row_ptr, const int* __restrict__ perm,
    const float* __restrict__ als_pp, const float* __restrict__ ald_pp,
    const float* __restrict__ als_cp, const float* __restrict__ ald_cp,
    const u16* __restrict__ h_p, const u16* __restrict__ h_c,
    u16* __restrict__ r_pp, u16* __restrict__ r_cp)
{
    int d2 = blockIdx.x * 16 + (threadIdx.x >> 4);
    int lane = threadIdx.x & 63;
    int l16 = lane & 15;
    int grp = lane & 48;
    int head = l16 >> 1;
    const float* als; const float* ald; const u16* hs; u16* out; int d;
    if (d2 < NP) { d = d2;      als = als_pp; ald = ald_pp; hs = h_p; out = r_pp; }
    else         { d = d2 - NP; als = als_cp; ald = ald_cp; hs = h_c; out = r_cp; }
    int beg = row_ptr[d2], end = row_ptr[d2 + 1];
    int n = end - beg;
    float ald_h = ald[(size_t)d * 8 + head];
    float dsum = 0.f;
    float acc[8] = {0.f, 0.f, 0.f, 0.f, 0.f, 0.f, 0.f, 0.f};
    for (int base = 0; base < n; base += 16) {
        int cnt = min(16, n - base);
        int my = (base + l16 < n) ? perm[beg + base + l16] : 0;
        int src = __shfl(my, grp, 64);
        float a_next = als[(size_t)src * 8 + head];
        uint4 hv_next = *(const uint4*)(hs + (size_t)src * 128 + l16 * 8);
        for (int j = 0; j < cnt; ++j) {
            float a_cur = a_next;
            uint4 hv = hv_next;
            if (j + 1 < cnt) {
                int s2 = __shfl(my, grp + j + 1, 64);
                a_next = als[(size_t)s2 * 8 + head];
                hv_next = *(const uint4*)(hs + (size_t)s2 * 128 + l16 * 8);
            }
            float a = a_cur + ald_h;
            a = a >= 0.f ? a : 0.2f * a;
            float w = __expf(a);
            dsum += w;
            u32 uu[4] = {hv.x, hv.y, hv.z, hv.w};
#pragma unroll
            for (int q = 0; q < 4; ++q) {
                acc[2 * q]     = fmaf(bf2f((u16)(uu[q] & 0xFFFFu)), w, acc[2 * q]);
                acc[2 * q + 1] = fmaf(bf2f((u16)(uu[q] >> 16)),     w, acc[2 * q + 1]);
            }
        }
    }
    float inv = 1.f / (dsum + 1e-16f);
    uint4 o;
    o.x = pack2(fmaxf(acc[0] * inv, 0.f), fmaxf(acc[1] * inv, 0.f));
    o.y = pack2(fmaxf(acc[2] * inv, 0.f), fmaxf(acc[3] * inv, 0.f));
    o.z = pack2(fmaxf(acc[4] * inv, 0.f), fmaxf(acc[5] * inv, 0.f));
    o.w = pack2(fmaxf(acc[6] * inv, 0.f), fmaxf(acc[7] * inv, 0.f));
    *(uint4*)(out + (size_t)d * 128 + l16 * 8) = o;
}

// ===== sem: A and B(WkT) direct-from-global; tanh colsum dotted with q -> vsum =====
__global__ __launch_bounds__(256) void sem_mfma(
    const u16* __restrict__ r0, const u16* __restrict__ r1,
    const u16* __restrict__ WkT, const float* __restrict__ bk,
    const float* __restrict__ q, float* __restrict__ vsum)
{
    __shared__ float red[4][128];
    __shared__ float sq_[128];
    __shared__ float dotb[128];
    int t = threadIdx.x;
    const u16* src = blockIdx.y ? r1 : r0;
    if (t < 128) sq_[t] = q[t];
    int wave = t >> 6, lane = t & 63;
    int fr = lane & 15, fq = lane >> 4;
    size_t arow = (size_t)blockIdx.x * 64 + wave * 16 + fr;
    const u16* ap = src + arow * 128 + fq * 8;
    short8v afr[4];
#pragma unroll
    for (int ks = 0; ks < 4; ++ks) afr[ks] = *(const short8v*)(ap + ks * 32);
    f32x4 acc[8];
#pragma unroll
    for (int nt = 0; nt < 8; ++nt) { float bb = bk[nt * 16 + fr]; acc[nt] = (f32x4){bb, bb, bb, bb}; }
#pragma unroll
    for (int ks = 0; ks < 4; ++ks) {
#pragma unroll
        for (int nt = 0; nt < 8; ++nt) {
            short8v bv = *(const short8v*)(WkT + (nt * 16 + fr) * 128 + ks * 32 + fq * 8);
            acc[nt] = __builtin_amdgcn_mfma_f32_16x16x32_bf16(afr[ks], bv, acc[nt], 0, 0, 0);
        }
    }
#pragma unroll
    for (int nt = 0; nt < 8; ++nt) {
        f32x4 v = acc[nt];
        float s = tanh_fast(v[0]) + tanh_fast(v[1]) + tanh_fast(v[2]) + tanh_fast(v[3]);
        s += __shfl_xor(s, 16, 64);
        s += __shfl_xor(s, 32, 64);
        if (lane < 16) red[wave][nt * 16 + lane] = s;
    }
    __syncthreads();
    if (t < 128) dotb[t] = (red[0][t] + red[1][t] + red[2][t] + red[3][t]) * sq_[t];
    __syncthreads();
    if (t < 64) {
        float v = dotb[t] + dotb[t + 64];
#pragma unroll
        for (int off = 32; off >= 1; off >>= 1) v += __shfl_xor(v, off, 64);
        if (t == 0) atomicAdd(&vsum[blockIdx.y], v);
    }
}

// ==== MLP1: A = (a0*r_cp + a1*r_pp) in-register; B(W1T) direct; BN stats atomics ====
__global__ __launch_bounds__(256) void mlp1_mfma(
    const u16* __restrict__ rcp, const u16* __restrict__ rpp, const float* __restrict__ vsum,
    const u16* __restrict__ W1T, const float* __restrict__ b1,
    u16* __restrict__ z1, float* __restrict__ sum1, float* __restrict__ sq1)
{
    __shared__ float redS[4][128];
    __shared__ float redQ[4][128];
    int t = threadIdx.x;
    float v0 = vsum[0] * (1.f / (float)NP), v1 = vsum[1] * (1.f / (float)NP);
    float mx = fmaxf(v0, v1);
    float e0 = __expf(v0 - mx), e1 = __expf(v1 - mx);
    float is = 1.f / (e0 + e1);
    float a0 = e0 * is, a1 = e1 * is;
    int wave = t >> 6, lane = t & 63;
    int fr = lane & 15, fq = lane >> 4;
    size_t row0 = (size_t)blockIdx.x * 64;
    size_t arow = row0 + wave * 16 + fr;
    const u16* rc = rcp + arow * 128 + fq * 8;
    const u16* rp = rpp + arow * 128 + fq * 8;
    uint4 uc[4], up[4];
#pragma unroll
    for (int ks = 0; ks < 4; ++ks) {
        uc[ks] = *(const uint4*)(rc + ks * 32);
        up[ks] = *(const uint4*)(rp + ks * 32);
    }
    f32x4 acc[8];
#pragma unroll
    for (int nt = 0; nt < 8; ++nt) { float bb = b1[nt * 16 + fr]; acc[nt] = (f32x4){bb, bb, bb, bb}; }
#pragma unroll
    for (int ks = 0; ks < 4; ++ks) {
        u32 cu[4] = {uc[ks].x, uc[ks].y, uc[ks].z, uc[ks].w};
        u32 pu[4] = {up[ks].x, up[ks].y, up[ks].z, up[ks].w};
        u32 pw[4];
#pragma unroll
        for (int j = 0; j < 4; ++j) {
            float lo = a0 * bf2f((u16)(cu[j] & 0xFFFFu)) + a1 * bf2f((u16)(pu[j] & 0xFFFFu));
            float hi = a0 * bf2f((u16)(cu[j] >> 16))     + a1 * bf2f((u16)(pu[j] >> 16));
            pw[j] = pack2(lo, hi);
        }
        short8v a = mk8(pw[0], pw[1], pw[2], pw[3]);
#pragma unroll
        for (int nt = 0; nt < 8; ++nt) {
            short8v bv = *(const short8v*)(W1T + (nt * 16 + fr) * 128 + ks * 32 + fq * 8);
            acc[nt] = __builtin_amdgcn_mfma_f32_16x16x32_bf16(a, bv, acc[nt], 0, 0, 0);
        }
    }
    size_t rbase = row0 + wave * 16 + fq * 4;
#pragma unroll
    for (int nt = 0; nt < 8; ++nt) {
        f32x4 v = acc[nt];
        int col = nt * 16 + fr;
#pragma unroll
        for (int rg = 0; rg < 4; ++rg)
            z1[(rbase + rg) * 128 + col] = f2bf(v[rg]);
        float s = v[0] + v[1] + v[2] + v[3];
        float qq = v[0] * v[0] + v[1] * v[1] + v[2] * v[2] + v[3] * v[3];
        s += __shfl_xor(s, 16, 64);  s += __shfl_xor(s, 32, 64);
        qq += __shfl_xor(qq, 16, 64); qq += __shfl_xor(qq, 32, 64);
        if (lane < 16) { redS[wave][col] = s; redQ[wave][col] = qq; }
    }
    __syncthreads();
    if (t < 128) {
        atomicAdd(&sum1[t], redS[0][t] + redS[1][t] + redS[2][t] + redS[3][t]);
        atomicAdd(&sq1[t],  redQ[0][t] + redQ[1][t] + redQ[2][t] + redQ[3][t]);
    }
}

// ===== MLP2: A = relu(bn(z1)) in-register; B(W2T) direct; BN2 stats atomics =====
__global__ __launch_bounds__(256) void mlp2_mfma(
    const u16* __restrict__ z1,
    const float* __restrict__ sum1, const float* __restrict__ sq1,
    const float* __restrict__ g1, const float* __restrict__ be1,
    const u16* __restrict__ W2T, const float* __restrict__ b2,
    u16* __restrict__ z2, float* __restrict__ sum2, float* __restrict__ sq2)
{
    __shared__ float sSc[128], sSh[128];
    __shared__ float redS[4][64], redQ[4][64];
    int t = threadIdx.x;
    if (t < 128) {
        float mu = sum1[t] * (1.f / (float)NP);
        float var = sq1[t] * (1.f / (float)NP) - mu * mu;
        float sc = g1[t] * rsqrtf(var + 1e-5f);
        sSc[t] = sc;
        sSh[t] = be1[t] - mu * sc;
    }
    __syncthreads();
    int wave = t >> 6, lane = t & 63;
    int fr = lane & 15, fq = lane >> 4;
    size_t row0 = (size_t)blockIdx.x * 64;
    size_t arow = row0 + wave * 16 + fr;
    const u16* zp = z1 + arow * 128 + fq * 8;
    uint4 uz[4];
#pragma unroll
    for (int ks = 0; ks < 4; ++ks) uz[ks] = *(const uint4*)(zp + ks * 32);
    f32x4 acc[4];
#pragma unroll
    for (int nt = 0; nt < 4; ++nt) { float bb = b2[nt * 16 + fr]; acc[nt] = (f32x4){bb, bb, bb, bb}; }
#pragma unroll
    for (int ks = 0; ks < 4; ++ks) {
        u32 zu[4] = {uz[ks].x, uz[ks].y, uz[ks].z, uz[ks].w};
        u32 pw[4];
        int c0 = ks * 32 + fq * 8;
#pragma unroll
        for (int j = 0; j < 4; ++j) {
            int c = c0 + 2 * j;
            float lo = fmaxf(bf2f((u16)(zu[j] & 0xFFFFu)) * sSc[c] + sSh[c], 0.f);
            float hi = fmaxf(bf2f((u16)(zu[j] >> 16)) * sSc[c + 1] + sSh[c + 1], 0.f);
            pw[j] = pack2(lo, hi);
        }
        short8v a = mk8(pw[0], pw[1], pw[2], pw[3]);
#pragma unroll
        for (int nt = 0; nt < 4; ++nt) {
            short8v bv = *(const short8v*)(W2T + (nt * 16 + fr) * 128 + ks * 32 + fq * 8);
            acc[nt] = __builtin_amdgcn_mfma_f32_16x16x32_bf16(a, bv, acc[nt], 0, 0, 0);
        }
    }
    size_t rbase = row0 + wave * 16 + fq * 4;
#pragma unroll
    for (int nt = 0; nt < 4; ++nt) {
        f32x4 v = acc[nt];
        int col = nt * 16 + fr;
#pragma unroll
        for (int rg = 0; rg < 4; ++rg)
            z2[(rbase + rg) * 64 + col] = f2bf(v[rg]);
        float s = v[0] + v[1] + v[2] + v[3];
        float qq = v[0] * v[0] + v[1] * v[1] + v[2] * v[2] + v[3] * v[3];
        s += __shfl_xor(s, 16, 64);  s += __shfl_xor(s, 32, 64);
        qq += __shfl_xor(qq, 16, 64); qq += __shfl_xor(qq, 32, 64);
        if (lane < 16) { redS[wave][col] = s; redQ[wave][col] = qq; }
    }
    __syncthreads();
    if (t < 64) {
        atomicAdd(&sum2[t], redS[0][t] + redS[1][t] + redS[2][t] + redS[3][t]);
        atomicAdd(&sq2[t],  redQ[0][t] + redQ[1][t] + redQ[2][t] + redQ[3][t]);
    }
}

// ===== final: sigmoid(relu(bn(z2)) @ W3 + b3), bf16 z2, BN inline =====
__global__ __launch_bounds__(64) void final_kernel(
    const u16* __restrict__ z2,
    const float* __restrict__ sum2, const float* __restrict__ sq2,
    const float* __restrict__ g2, const float* __restrict__ be2,
    const float* __restrict__ W3, const float* __restrict__ b3, float* __restrict__ out)
{
    __shared__ float sh[64][65];
    __shared__ float sw[64];
    int t = threadIdx.x; // 64
    float mu = sum2[t] * (1.f / (float)NP);
    float var = sq2[t] * (1.f / (float)NP) - mu * mu;
    float sc = g2[t] * rsqrtf(var + 1e-5f);
    float sh2 = be2[t] - mu * sc;
    size_t row0 = (size_t)blockIdx.x * 64;
    sw[t] = W3[t];
    for (int j = 0; j < 64; ++j) {
        float v = bf2f(z2[(row0 + j) * 64 + t]) * sc + sh2;
        sh[j][t] = v > 0.f ? v : 0.f;
    }
    __syncthreads();
    float acc = b3[0];
#pragma unroll 16
    for (int k = 0; k < 64; ++k) acc = fmaf(sh[t][k], sw[k], acc);
    out[row0 + t] = 1.f / (1.f + __expf(-acc));
}

extern "C" void kernel_launch(void* const* d_in, const int* in_sizes, int n_in,
                              void* d_out, int out_size, void* d_ws, size_t ws_size,
                              hipStream_t stream) {
    const float* x_c      = (const float*)d_in[0];
    const float* x_p      = (const float*)d_in[1];
    const int*   e_src_cp = (const int*)d_in[2];
    const int*   e_dst_cp = (const int*)d_in[3];
    const int*   e_src_pp = (const int*)d_in[4];
    const int*   e_dst_pp = (const int*)d_in[5];
    const float* W_c      = (const float*)d_in[6];
    const float* b_c      = (const float*)d_in[7];
    const float* W_p      = (const float*)d_in[8];
    const float* b_p      = (const float*)d_in[9];
    const float* a_src_cp = (const float*)d_in[10];
    const float* a_dst_cp = (const float*)d_in[11];
    const float* a_src_pp = (const float*)d_in[12];
    const float* a_dst_pp = (const float*)d_in[13];
    const float* Wk       = (const float*)d_in[14];
    const float* bk       = (const float*)d_in[15];
    const float* q_sem    = (const float*)d_in[16];
    const float* W1       = (const float*)d_in[17];
    const float* b1       = (const float*)d_in[18];
    const float* g1       = (const float*)d_in[19];
    const float* be1      = (const float*)d_in[20];
    const float* W2       = (const float*)d_in[21];
    const float* b2       = (const float*)d_in[22];
    const float* g2       = (const float*)d_in[23];
    const float* be2      = (const float*)d_in[24];
    const float* W3       = (const float*)d_in[25];
    const float* b3       = (const float*)d_in[26];

    // ---- byte-offset workspace layout (extent 211,347,712 B; 212,809,472 proven OK) ----
    char* ws = (char*)d_ws;
    u16*   h_p    = (u16*)  (ws +          0);  // 51,200,000
    u16*   h_c    = (u16*)  (ws +  51200000);   // 25,600,000
    float* al_c   = (float*)(ws +  76800000);   //  3,200,000
    float* al_dcp = (float*)(ws +  80000000);   //  6,400,000
    float* al_spp = (float*)(ws +  86400000);
    float* al_dpp = (float*)(ws +  92800000);
    int*   row_ptr= (int*)  (ws +  99200000);   // (NN2+1)*4 padded -> 100,800,256
    int*   perm   = (int*)  (ws + 100800256);   // 2NE*4 -> 108,800,256
    u64*   pairs  = (u64*)  (ws + 108800256);   // 2NE*8 -> 124,800,256 [dead after bsort]
    u16*   r_pp   = (u16*)  (ws + 108800256);   // NP*128 bf16 (overlays pairs, dead by gather)
    u16*   r_cp   = (u16*)  (ws + 160000256);   // NP*128 bf16 -> 211,200,256
    float* small  = (float*)(ws + 211200256);   // 16384 B (zeroed once) -> 211,216,640
    u16*   WcT    = (u16*)  (ws + 211216640);   // 8192*2  -> 211,233,024
    u16*   WpT    = (u16*)  (ws + 211233024);   // 8192*2  -> 211,249,408
    u16*   WkT    = (u16*)  (ws + 211249408);   // 16384*2 -> 211,282,176
    u16*   W1T    = (u16*)  (ws + 211282176);   // 16384*2 -> 211,314,944
    u16*   W2T    = (u16*)  (ws + 211314944);   // 8192*2  -> 211,331,328

    float* vsum   = small;        // 2
    float* sum1   = small + 128;  // 128
    float* sq1    = small + 256;  // 128
    float* sum2   = small + 384;  // 64
    float* sq2    = small + 448;  // 64
    int*   bcnt   = (int*)(small + 512);   // 391
    int*   bbase  = (int*)(small + 1024);  // 392
    int*   bcur   = (int*)(small + 1536);  // 391

    // aliases over dead regions
    u16*   z1 = h_p;                   // bf16 NP*128 at [0,51.2M): h_p dead after gather
    u16*   z2 = (u16*)(ws + 51200000); // bf16 NP*64 = 25.6MB: h_c dead after gather

    hipMemsetAsync(small, 0, 16384, stream);

    // one-time bf16 transposed weight tables
    wconv<<<224, 256, 0, stream>>>(W_c, W_p, Wk, W1, W2, WcT, WpT, WkT, W1T, W2T);

    // projections (MFMA, A+B direct) + fused logits; idle customer blocks run bhist
    {
        dim3 g(NP / 64, 2);
        proj_both<<<g, 256, 0, stream>>>(x_c, WcT, b_c, x_p, WpT, b_p, h_c, h_p,
                                         a_src_cp, a_dst_cp, a_src_pp, a_dst_pp,
                                         al_c, al_dcp, al_spp, al_dpp,
                                         e_dst_pp, e_dst_cp, bcnt);
    }

    // ---- bucketed CSR over both metapaths ----
    bscan<<<1, 512, 0, stream>>>(bcnt, bbase, bcur, row_ptr);
    bplace<<<NBLK_E, 256, 0, stream>>>(e_src_pp, e_dst_pp, e_src_cp, e_dst_cp, bcur, pairs);
    bsort<<<NBUK, 256, 0, stream>>>(pairs, bbase, row_ptr, perm);

    gather2<<<NN2 / 16, 256, 0, stream>>>(row_ptr, perm,
                                          al_spp, al_dpp, al_c, al_dcp,
                                          h_p, h_c, r_pp, r_cp);

    // semantic attention (A+B direct, dot with q fused)
    {
        dim3 gs(NP / 64, 2);
        sem_mfma<<<gs, 256, 0, stream>>>(r_cp, r_pp, WkT, bk, q_sem, vsum);
    }

    // MLP + BN (A in-register; B direct; stats via atomics; BN affine inline)
    mlp1_mfma<<<NP / 64, 256, 0, stream>>>(r_cp, r_pp, vsum, W1T, b1, z1, sum1, sq1);
    mlp2_mfma<<<NP / 64, 256, 0, stream>>>(z1, sum1, sq1, g1, be1, W2T, b2, z2, sum2, sq2);
    final_kernel<<<NP / 64, 64, 0, stream>>>(z2, sum2, sq2, g2, be2, W3, b3, (float*)d_out);
}

// Round 13
// 470.270 us; speedup vs baseline: 1.2312x; 1.2312x over previous
//
#include <hip/hip_runtime.h>
#include <hip/hip_bf16.h>

#define NC 100000
#define NP 200000
#define NE 1000000
#define NN2 (2 * NP)      // combined dst-node space (pp then cp)
#define NBUK 391          // ceil(NN2/1024)
#define ECHUNK 8192
#define NBLK_E 245        // ceil(2*NE/8192)
#define NBLK_C 1563       // ceil(NC/64)

typedef unsigned short u16;
typedef unsigned int u32;
typedef unsigned long long u64;
typedef __attribute__((ext_vector_type(8))) short short8v;  // 8 bf16 (4 VGPRs)
typedef __attribute__((ext_vector_type(4))) float f32x4;

__device__ __forceinline__ float bf2f(u16 v) {
    union { u32 u; float f; } c; c.u = ((u32)v) << 16; return c.f;
}
__device__ __forceinline__ u16 f2bf(float f) {
    union { float f; u32 u; } c; c.f = f;
    u32 u = c.u;
    return (u16)((u + 0x7FFFu + ((u >> 16) & 1u)) >> 16); // RNE
}
__device__ __forceinline__ u32 pack2(float lo, float hi) {
    return (u32)f2bf(lo) | ((u32)f2bf(hi) << 16);
}
__device__ __forceinline__ float tanh_fast(float x) {
    return 1.f - 2.f / (__expf(2.f * x) + 1.f);
}

// ========== proj (both types): h = bf16(x @ W + b) via MFMA, + fused logits ==========
__global__ __launch_bounds__(256) void proj_both(
    const float* __restrict__ x_c, const float* __restrict__ W_c, const float* __restrict__ b_c,
    const float* __restrict__ x_p, const float* __restrict__ W_p, const float* __restrict__ b_p,
    u16* __restrict__ out_c, u16* __restrict__ out_p,
    const float* __restrict__ a_cp_s,
    const float* __restrict__ a_cp_d, const float* __restrict__ a_pp_s,
    const float* __restrict__ a_pp_d,
    float* __restrict__ al_c, float* __restrict__ al_dcp,
    float* __restrict__ al_spp, float* __restrict__ al_dpp)
{
    const float* x; const float* W; const float* b; u16* h; int N;
    int py = blockIdx.y;
    if (py == 0) { x = x_c; W = W_c; b = b_c; h = out_c; N = NC; }
    else         { x = x_p; W = W_p; b = b_p; h = out_p; N = NP; }
    size_t row0 = (size_t)blockIdx.x * 64;
    if (row0 >= (size_t)N) return;
    __shared__ alignas(16) u16 sBT[128 * 72];
    __shared__ alignas(16) u16 sA[64 * 72];
    __shared__ alignas(16) u16 hTile[64 * 136];
    __shared__ float aV[3][128];
    int t = threadIdx.x;
    if (t < 128) {
        aV[0][t] = py ? a_cp_d[t] : a_cp_s[t];
        aV[1][t] = py ? a_pp_s[t] : 0.f;
        aV[2][t] = py ? a_pp_d[t] : 0.f;
    }
    for (int i = t; i < 128 * 8; i += 256) {
        int n = i & 127, kb = i >> 7;
        u32 p[4];
#pragma unroll
        for (int j = 0; j < 4; ++j)
            p[j] = pack2(W[(kb * 8 + 2 * j) * 128 + n], W[(kb * 8 + 2 * j + 1) * 128 + n]);
        *(uint4*)(&sBT[n * 72 + kb * 8]) = make_uint4(p[0], p[1], p[2], p[3]);
    }
    for (int i = t; i < 64 * 8; i += 256) {
        int r = i >> 3, c8 = (i & 7) * 8;
        u32 p[4];
        if (row0 + r < (size_t)N) {
            const float* src = x + (row0 + r) * 64 + c8;
            float4 v0 = *(const float4*)src;
            float4 v1 = *(const float4*)(src + 4);
            p[0] = pack2(v0.x, v0.y); p[1] = pack2(v0.z, v0.w);
            p[2] = pack2(v1.x, v1.y); p[3] = pack2(v1.z, v1.w);
        } else { p[0] = p[1] = p[2] = p[3] = 0; }
        *(uint4*)(&sA[r * 72 + c8]) = make_uint4(p[0], p[1], p[2], p[3]);
    }
    __syncthreads();
    int wave = t >> 6, lane = t & 63;
    int fr = lane & 15, fq = lane >> 4;
    const u16* pA = sA + (wave * 16 + fr) * 72 + fq * 8;
    const u16* pB = sBT + fr * 72 + fq * 8;
    f32x4 acc[8];
#pragma unroll
    for (int nt = 0; nt < 8; ++nt) { float bb = b[nt * 16 + fr]; acc[nt] = (f32x4){bb, bb, bb, bb}; }
#pragma unroll
    for (int ks = 0; ks < 2; ++ks) {
        short8v a = *(const short8v*)(pA + ks * 32);
#pragma unroll
        for (int nt = 0; nt < 8; ++nt) {
            short8v bv = *(const short8v*)(pB + nt * 16 * 72 + ks * 32);
            acc[nt] = __builtin_amdgcn_mfma_f32_16x16x32_bf16(a, bv, acc[nt], 0, 0, 0);
        }
    }
    size_t rbase = row0 + wave * 16 + fq * 4;
    int lrow0 = wave * 16 + fq * 4;
#pragma unroll
    for (int nt = 0; nt < 8; ++nt) {
        int col = nt * 16 + fr;
#pragma unroll
        for (int rg = 0; rg < 4; ++rg) {
            size_t rr = rbase + rg;
            u16 hv = f2bf(acc[nt][rg]);
            if (rr < (size_t)N) h[rr * 128 + col] = hv;
            hTile[(lrow0 + rg) * 136 + col] = hv;
        }
    }
    __syncthreads();
    // fused per-head logits from the LDS h tile
    int row = t >> 2;
    size_t grow = row0 + row;
    if (grow < (size_t)N) {
#pragma unroll
        for (int hd = t & 3; hd < 8; hd += 4) {
            const u16* hp = &hTile[row * 136 + hd * 16];
            uint4 u0_ = *(const uint4*)hp;
            uint4 u1_ = *(const uint4*)(hp + 8);
            u32 uu[8] = {u0_.x, u0_.y, u0_.z, u0_.w, u1_.x, u1_.y, u1_.z, u1_.w};
            float p0 = 0.f, p1 = 0.f, p2 = 0.f;
#pragma unroll
            for (int j = 0; j < 8; ++j) {
                float lo = bf2f((u16)(uu[j] & 0xFFFFu));
                float hi = bf2f((u16)(uu[j] >> 16));
                int c = hd * 16 + 2 * j;
                p0 += lo * aV[0][c] + hi * aV[0][c + 1];
                p1 += lo * aV[1][c] + hi * aV[1][c + 1];
                p2 += lo * aV[2][c] + hi * aV[2][c + 1];
            }
            if (py == 0) {
                al_c[grow * 8 + hd] = p0;
            } else {
                al_dcp[grow * 8 + hd] = p0;
                al_spp[grow * 8 + hd] = p1;
                al_dpp[grow * 8 + hd] = p2;
            }
        }
    }
}

// ================= bucketed CSR build =================
__global__ __launch_bounds__(256) void bhist(const int* __restrict__ dpp, const int* __restrict__ dcp,
                                             int* __restrict__ bcnt)
{
    __shared__ int h[NBUK];
    int t = threadIdx.x;
    for (int i = t; i < NBUK; i += 256) h[i] = 0;
    __syncthreads();
    int base = blockIdx.x * ECHUNK;
    int lim = min(ECHUNK, 2 * NE - base);
    for (int i = t; i < lim; i += 256) {
        int e = base + i;
        int d2 = (e < NE) ? dpp[e] : NP + dcp[e - NE];
        atomicAdd(&h[d2 >> 10], 1);
    }
    __syncthreads();
    for (int i = t; i < NBUK; i += 256) if (h[i]) atomicAdd(&bcnt[i], h[i]);
}

__global__ __launch_bounds__(512) void bscan(const int* __restrict__ bcnt, int* __restrict__ bbase,
                                             int* __restrict__ bcur, int* __restrict__ row_ptr)
{
    __shared__ int s[512];
    int t = threadIdx.x;
    int v = (t < NBUK) ? bcnt[t] : 0;
    s[t] = v;
    __syncthreads();
    for (int off = 1; off < 512; off <<= 1) {
        int x = (t >= off) ? s[t - off] : 0;
        __syncthreads();
        s[t] += x;
        __syncthreads();
    }
    if (t < NBUK) { bbase[t] = s[t] - v; bcur[t] = s[t] - v; }
    if (t == 0) { bbase[NBUK] = 2 * NE; row_ptr[NN2] = 2 * NE; }
}

__global__ __launch_bounds__(256) void bplace(
    const int* __restrict__ spp, const int* __restrict__ dpp,
    const int* __restrict__ scp, const int* __restrict__ dcp,
    int* __restrict__ bcur, u64* __restrict__ pairs)
{
    __shared__ int h[NBUK];
    __shared__ int rk[NBUK];
    int t = threadIdx.x;
    for (int i = t; i < NBUK; i += 256) h[i] = 0;
    __syncthreads();
    int base = blockIdx.x * ECHUNK;
    int lim = min(ECHUNK, 2 * NE - base);
    for (int i = t; i < lim; i += 256) {
        int e = base + i;
        int d2 = (e < NE) ? dpp[e] : NP + dcp[e - NE];
        atomicAdd(&h[d2 >> 10], 1);
    }
    __syncthreads();
    for (int i = t; i < NBUK; i += 256) {
        int c = h[i];
        h[i] = c ? atomicAdd(&bcur[i], c) : 0;
        rk[i] = 0;
    }
    __syncthreads();
    for (int i = t; i < lim; i += 256) {
        int e = base + i;
        int d2, src;
        if (e < NE) { d2 = dpp[e];      src = spp[e]; }
        else        { d2 = NP + dcp[e - NE]; src = scp[e - NE]; }
        int b = d2 >> 10;
        int r = atomicAdd(&rk[b], 1);
        pairs[h[b] + r] = ((u64)(u32)d2 << 32) | (u32)src;
    }
}

__global__ __launch_bounds__(256) void bsort(
    const u64* __restrict__ pairs, const int* __restrict__ bbase,
    int* __restrict__ row_ptr, int* __restrict__ perm)
{
    __shared__ int cnt[1024];
    __shared__ int sc[256];
    int b = blockIdx.x, t = threadIdx.x;
    int beg = bbase[b], end = bbase[b + 1];
    for (int i = t; i < 1024; i += 256) cnt[i] = 0;
    __syncthreads();
    for (int i = beg + t; i < end; i += 256) {
        int d2 = (int)(pairs[i] >> 32);
        atomicAdd(&cnt[d2 & 1023], 1);
    }
    __syncthreads();
    int b4 = t * 4;
    int c0 = cnt[b4], c1 = cnt[b4 + 1], c2 = cnt[b4 + 2], c3 = cnt[b4 + 3];
    int s = c0 + c1 + c2 + c3;
    sc[t] = s;
    __syncthreads();
    for (int off = 1; off < 256; off <<= 1) {
        int x = (t >= off) ? sc[t - off] : 0;
        __syncthreads();
        sc[t] += x;
        __syncthreads();
    }
    int run = sc[t] - s;
    int o0 = run, o1 = run + c0, o2 = o1 + c1, o3 = o2 + c2;
    cnt[b4] = o0; cnt[b4 + 1] = o1; cnt[b4 + 2] = o2; cnt[b4 + 3] = o3;
    int gidx = b * 1024 + b4;
    if (gidx     < NN2) row_ptr[gidx]     = beg + o0;
    if (gidx + 1 < NN2) row_ptr[gidx + 1] = beg + o1;
    if (gidx + 2 < NN2) row_ptr[gidx + 2] = beg + o2;
    if (gidx + 3 < NN2) row_ptr[gidx + 3] = beg + o3;
    __syncthreads();
    for (int i = beg + t; i < end; i += 256) {
        u64 p = pairs[i];
        int d2 = (int)(p >> 32);
        int r = atomicAdd(&cnt[d2 & 1023], 1);
        perm[beg + r] = (int)(p & 0xFFFFFFFFull);
    }
}

// ===== gather (proven single-chain): 16 lanes/dst, perm preload + 1-deep pipeline =====
__global__ __launch_bounds__(256) void gather2(
    const int* __restrict__ row_ptr, const int* __restrict__ perm,
    const float* __restrict__ als_pp, const float* __restrict__ ald_pp,
    const float* __restrict__ als_cp, const float* __restrict__ ald_cp,
    const u16* __restrict__ h_p, const u16* __restrict__ h_c,
    u16* __restrict__ r_pp, u16* __restrict__ r_cp)
{
    int d2 = blockIdx.x * 16 + (threadIdx.x >> 4);
    int lane = threadIdx.x & 63;
    int l16 = lane & 15;
    int grp = lane & 48;
    int head = l16 >> 1;
    const float* als; const float* ald; const u16* hs; u16* out; int d;
    if (d2 < NP) { d = d2;      als = als_pp; ald = ald_pp; hs = h_p; out = r_pp; }
    else         { d = d2 - NP; als = als_cp; ald = ald_cp; hs = h_c; out = r_cp; }
    int beg = row_ptr[d2], end = row_ptr[d2 + 1];
    int n = end - beg;
    float ald_h = ald[(size_t)d * 8 + head];
    float dsum = 0.f;
    float acc[8] = {0.f, 0.f, 0.f, 0.f, 0.f, 0.f, 0.f, 0.f};
    for (int base = 0; base < n; base += 16) {
        int cnt = min(16, n - base);
        int my = (base + l16 < n) ? perm[beg + base + l16] : 0;
        int src = __shfl(my, grp, 64);
        float a_next = als[(size_t)src * 8 + head];
        uint4 hv_next = *(const uint4*)(hs + (size_t)src * 128 + l16 * 8);
        for (int j = 0; j < cnt; ++j) {
            float a_cur = a_next;
            uint4 hv = hv_next;
            if (j + 1 < cnt) {
                int s2 = __shfl(my, grp + j + 1, 64);
                a_next = als[(size_t)s2 * 8 + head];
                hv_next = *(const uint4*)(hs + (size_t)s2 * 128 + l16 * 8);
            }
            float a = a_cur + ald_h;
            a = a >= 0.f ? a : 0.2f * a;
            float w = __expf(a);
            dsum += w;
            u32 uu[4] = {hv.x, hv.y, hv.z, hv.w};
#pragma unroll
            for (int q = 0; q < 4; ++q) {
                acc[2 * q]     = fmaf(bf2f((u16)(uu[q] & 0xFFFFu)), w, acc[2 * q]);
                acc[2 * q + 1] = fmaf(bf2f((u16)(uu[q] >> 16)),     w, acc[2 * q + 1]);
            }
        }
    }
    float inv = 1.f / (dsum + 1e-16f);
    uint4 o;
    o.x = pack2(fmaxf(acc[0] * inv, 0.f), fmaxf(acc[1] * inv, 0.f));
    o.y = pack2(fmaxf(acc[2] * inv, 0.f), fmaxf(acc[3] * inv, 0.f));
    o.z = pack2(fmaxf(acc[4] * inv, 0.f), fmaxf(acc[5] * inv, 0.f));
    o.w = pack2(fmaxf(acc[6] * inv, 0.f), fmaxf(acc[7] * inv, 0.f));
    *(uint4*)(out + (size_t)d * 128 + l16 * 8) = o;
}

// ================= sem: per-block col-sums of tanh(r_m @ Wk + bk) =================
__global__ __launch_bounds__(256) void sem_mfma(
    const u16* __restrict__ r0, const u16* __restrict__ r1,
    const float* __restrict__ Wk, const float* __restrict__ bk,
    float* __restrict__ part)   // [2][3125][128]
{
    __shared__ alignas(16) u16 sBT[128 * 136];
    __shared__ alignas(16) u16 sA[64 * 136];
    __shared__ float red[4][128];
    int t = threadIdx.x;
    const u16* src = blockIdx.y ? r1 : r0;
    for (int i = t; i < 128 * 16; i += 256) {
        int n = i & 127, kb = i >> 7;
        u32 p[4];
#pragma unroll
        for (int j = 0; j < 4; ++j)
            p[j] = pack2(Wk[(kb * 8 + 2 * j) * 128 + n], Wk[(kb * 8 + 2 * j + 1) * 128 + n]);
        *(uint4*)(&sBT[n * 136 + kb * 8]) = make_uint4(p[0], p[1], p[2], p[3]);
    }
    size_t row0 = (size_t)blockIdx.x * 64;
    for (int i = t; i < 64 * 16; i += 256) {
        int r = i >> 4, c8 = (i & 15) * 8;
        *(uint4*)(&sA[r * 136 + c8]) = *(const uint4*)(src + (row0 + r) * 128 + c8);
    }
    __syncthreads();
    int wave = t >> 6, lane = t & 63;
    int fr = lane & 15, fq = lane >> 4;
    const u16* pA = sA + (wave * 16 + fr) * 136 + fq * 8;
    const u16* pB = sBT + fr * 136 + fq * 8;
    f32x4 acc[8];
#pragma unroll
    for (int nt = 0; nt < 8; ++nt) { float bb = bk[nt * 16 + fr]; acc[nt] = (f32x4){bb, bb, bb, bb}; }
#pragma unroll
    for (int ks = 0; ks < 4; ++ks) {
        short8v a = *(const short8v*)(pA + ks * 32);
#pragma unroll
        for (int nt = 0; nt < 8; ++nt) {
            short8v bv = *(const short8v*)(pB + nt * 16 * 136 + ks * 32);
            acc[nt] = __builtin_amdgcn_mfma_f32_16x16x32_bf16(a, bv, acc[nt], 0, 0, 0);
        }
    }
#pragma unroll
    for (int nt = 0; nt < 8; ++nt) {
        f32x4 v = acc[nt];
        float s = tanh_fast(v[0]) + tanh_fast(v[1]) + tanh_fast(v[2]) + tanh_fast(v[3]);
        s += __shfl_xor(s, 16, 64);
        s += __shfl_xor(s, 32, 64);
        if (lane < 16) red[wave][nt * 16 + lane] = s;
    }
    __syncthreads();
    if (t < 128) {
        float s = red[0][t] + red[1][t] + red[2][t] + red[3][t];
        part[((size_t)blockIdx.y * gridDim.x + blockIdx.x) * 128 + t] = s;
    }
}

// ================= sem partial-dot =================
__global__ __launch_bounds__(256) void sem_dot(const float* __restrict__ part,
                                               const float* __restrict__ q, float* __restrict__ vsum)
{
    __shared__ float sq_[128];
    __shared__ float red[256];
    int t = threadIdx.x;
    if (t < 128) sq_[t] = q[t];
    __syncthreads();
    int c = t & 127, m = t >> 7;
    int i0 = blockIdx.x * 98;
    int i1 = i0 + 98; if (i1 > 3125) i1 = 3125;
    float acc = 0.f;
    for (int i = i0; i < i1; ++i)
        acc += part[((size_t)m * 3125 + i) * 128 + c] * sq_[c];
    red[t] = acc;
    __syncthreads();
    for (int off = 64; off >= 1; off >>= 1) {
        if ((t & 127) < off) red[t] += red[t + off];
        __syncthreads();
    }
    if ((t & 127) == 0) atomicAdd(&vsum[m], red[t]);
}

// ==== MLP1: z1 = (a0*r_cp + a1*r_pp) @ W1 + b1 (attn computed inline from vsum) ====
__global__ __launch_bounds__(256) void mlp1_mfma(
    const u16* __restrict__ rcp, const u16* __restrict__ rpp, const float* __restrict__ vsum,
    const float* __restrict__ W1, const float* __restrict__ b1,
    u16* __restrict__ z1, float* __restrict__ pS, float* __restrict__ pQ)
{
    __shared__ alignas(16) u16 sBT[128 * 136];
    __shared__ alignas(16) u16 sA[64 * 136];
    __shared__ float redS[4][128];
    __shared__ float redQ[4][128];
    int t = threadIdx.x;
    float v0 = vsum[0] * (1.f / (float)NP), v1 = vsum[1] * (1.f / (float)NP);
    float mx = fmaxf(v0, v1);
    float e0 = __expf(v0 - mx), e1 = __expf(v1 - mx);
    float is = 1.f / (e0 + e1);
    float a0 = e0 * is, a1 = e1 * is;
    for (int i = t; i < 128 * 16; i += 256) {
        int n = i & 127, kb = i >> 7;
        u32 p[4];
#pragma unroll
        for (int j = 0; j < 4; ++j)
            p[j] = pack2(W1[(kb * 8 + 2 * j) * 128 + n], W1[(kb * 8 + 2 * j + 1) * 128 + n]);
        *(uint4*)(&sBT[n * 136 + kb * 8]) = make_uint4(p[0], p[1], p[2], p[3]);
    }
    size_t row0 = (size_t)blockIdx.x * 64;
    for (int i = t; i < 64 * 16; i += 256) {
        int r = i >> 4, c8 = (i & 15) * 8;
        size_t gidx = (row0 + r) * 128 + c8;
        uint4 uc = *(const uint4*)(rcp + gidx);
        uint4 up = *(const uint4*)(rpp + gidx);
        u32 uuc[4] = {uc.x, uc.y, uc.z, uc.w};
        u32 uup[4] = {up.x, up.y, up.z, up.w};
        u32 p[4];
#pragma unroll
        for (int j = 0; j < 4; ++j) {
            float lo = a0 * bf2f((u16)(uuc[j] & 0xFFFFu)) + a1 * bf2f((u16)(uup[j] & 0xFFFFu));
            float hi = a0 * bf2f((u16)(uuc[j] >> 16))     + a1 * bf2f((u16)(uup[j] >> 16));
            p[j] = pack2(lo, hi);
        }
        *(uint4*)(&sA[r * 136 + c8]) = make_uint4(p[0], p[1], p[2], p[3]);
    }
    __syncthreads();
    int wave = t >> 6, lane = t & 63;
    int fr = lane & 15, fq = lane >> 4;
    const u16* pA = sA + (wave * 16 + fr) * 136 + fq * 8;
    const u16* pB = sBT + fr * 136 + fq * 8;
    f32x4 acc[8];
#pragma unroll
    for (int nt = 0; nt < 8; ++nt) { float bb = b1[nt * 16 + fr]; acc[nt] = (f32x4){bb, bb, bb, bb}; }
#pragma unroll
    for (int ks = 0; ks < 4; ++ks) {
        short8v a = *(const short8v*)(pA + ks * 32);
#pragma unroll
        for (int nt = 0; nt < 8; ++nt) {
            short8v bv = *(const short8v*)(pB + nt * 16 * 136 + ks * 32);
            acc[nt] = __builtin_amdgcn_mfma_f32_16x16x32_bf16(a, bv, acc[nt], 0, 0, 0);
        }
    }
    size_t rbase = row0 + wave * 16 + fq * 4;
#pragma unroll
    for (int nt = 0; nt < 8; ++nt) {
        f32x4 v = acc[nt];
        int col = nt * 16 + fr;
#pragma unroll
        for (int rg = 0; rg < 4; ++rg)
            z1[(rbase + rg) * 128 + col] = f2bf(v[rg]);
        float s = v[0] + v[1] + v[2] + v[3];
        float qq = v[0] * v[0] + v[1] * v[1] + v[2] * v[2] + v[3] * v[3];
        s += __shfl_xor(s, 16, 64);  s += __shfl_xor(s, 32, 64);
        qq += __shfl_xor(qq, 16, 64); qq += __shfl_xor(qq, 32, 64);
        if (lane < 16) { redS[wave][col] = s; redQ[wave][col] = qq; }
    }
    __syncthreads();
    if (t < 128) {
        pS[(size_t)blockIdx.x * 128 + t] = redS[0][t] + redS[1][t] + redS[2][t] + redS[3][t];
        pQ[(size_t)blockIdx.x * 128 + t] = redQ[0][t] + redQ[1][t] + redQ[2][t] + redQ[3][t];
    }
}

// ================= reduce BN partials [3125][C] -> sum/sq =================
__global__ __launch_bounds__(256) void stat_reduce(
    const float* __restrict__ pS, const float* __restrict__ pQ,
    float* __restrict__ sum, float* __restrict__ sq, int C)
{
    __shared__ float redS[256], redQ[256];
    int t = threadIdx.x;
    int c = t & (C - 1);
    int sub = t / C;
    int stride = 256 / C;
    int i0 = blockIdx.x * 125, i1 = i0 + 125;
    float s = 0.f, q = 0.f;
    for (int i = i0 + sub; i < i1; i += stride) {
        s += pS[(size_t)i * C + c];
        q += pQ[(size_t)i * C + c];
    }
    redS[t] = s; redQ[t] = q;
    __syncthreads();
    if (t < C) {
        for (int k = 1; k < stride; ++k) { s += redS[t + k * C]; q += redQ[t + k * C]; }
        atomicAdd(&sum[c], s);
        atomicAdd(&sq[c], q);
    }
}

// ===== MLP2: z2 = bf16(relu(bn(z1)) @ W2 + b2), BN scale/shift computed inline =====
__global__ __launch_bounds__(256) void mlp2_mfma(
    const u16* __restrict__ z1,
    const float* __restrict__ sum1, const float* __restrict__ sq1,
    const float* __restrict__ g1, const float* __restrict__ be1,
    const float* __restrict__ W2, const float* __restrict__ b2,
    u16* __restrict__ z2, float* __restrict__ pS, float* __restrict__ pQ)
{
    __shared__ alignas(16) u16 sBT[64 * 136];
    __shared__ alignas(16) u16 sA[64 * 136];
    __shared__ float sSc[128], sSh[128];
    __shared__ float redS[4][64], redQ[4][64];
    int t = threadIdx.x;
    if (t < 128) {
        float mu = sum1[t] * (1.f / (float)NP);
        float var = sq1[t] * (1.f / (float)NP) - mu * mu;
        float sc = g1[t] * rsqrtf(var + 1e-5f);
        sSc[t] = sc;
        sSh[t] = be1[t] - mu * sc;
    }
    for (int i = t; i < 64 * 16; i += 256) {
        int n = i & 63, kb = i >> 6;
        u32 p[4];
#pragma unroll
        for (int j = 0; j < 4; ++j)
            p[j] = pack2(W2[(kb * 8 + 2 * j) * 64 + n], W2[(kb * 8 + 2 * j + 1) * 64 + n]);
        *(uint4*)(&sBT[n * 136 + kb * 8]) = make_uint4(p[0], p[1], p[2], p[3]);
    }
    __syncthreads();
    size_t row0 = (size_t)blockIdx.x * 64;
    for (int i = t; i < 64 * 16; i += 256) {
        int r = i >> 4, c8 = (i & 15) * 8;
        uint4 up = *(const uint4*)(z1 + (row0 + r) * 128 + c8);
        u32 uu[4] = {up.x, up.y, up.z, up.w};
        u32 p[4];
#pragma unroll
        for (int j = 0; j < 4; ++j) {
            int c = c8 + 2 * j;
            float lo = fmaxf(bf2f((u16)(uu[j] & 0xFFFFu)) * sSc[c] + sSh[c], 0.f);
            float hi = fmaxf(bf2f((u16)(uu[j] >> 16)) * sSc[c + 1] + sSh[c + 1], 0.f);
            p[j] = pack2(lo, hi);
        }
        *(uint4*)(&sA[r * 136 + c8]) = make_uint4(p[0], p[1], p[2], p[3]);
    }
    __syncthreads();
    int wave = t >> 6, lane = t & 63;
    int fr = lane & 15, fq = lane >> 4;
    const u16* pA = sA + (wave * 16 + fr) * 136 + fq * 8;
    const u16* pB = sBT + fr * 136 + fq * 8;
    f32x4 acc[4];
#pragma unroll
    for (int nt = 0; nt < 4; ++nt) { float bb = b2[nt * 16 + fr]; acc[nt] = (f32x4){bb, bb, bb, bb}; }
#pragma unroll
    for (int ks = 0; ks < 4; ++ks) {
        short8v a = *(const short8v*)(pA + ks * 32);
#pragma unroll
        for (int nt = 0; nt < 4; ++nt) {
            short8v bv = *(const short8v*)(pB + nt * 16 * 136 + ks * 32);
            acc[nt] = __builtin_amdgcn_mfma_f32_16x16x32_bf16(a, bv, acc[nt], 0, 0, 0);
        }
    }
    size_t rbase = row0 + wave * 16 + fq * 4;
#pragma unroll
    for (int nt = 0; nt < 4; ++nt) {
        f32x4 v = acc[nt];
        int col = nt * 16 + fr;
#pragma unroll
        for (int rg = 0; rg < 4; ++rg)
            z2[(rbase + rg) * 64 + col] = f2bf(v[rg]);
        float s = v[0] + v[1] + v[2] + v[3];
        float qq = v[0] * v[0] + v[1] * v[1] + v[2] * v[2] + v[3] * v[3];
        s += __shfl_xor(s, 16, 64);  s += __shfl_xor(s, 32, 64);
        qq += __shfl_xor(qq, 16, 64); qq += __shfl_xor(qq, 32, 64);
        if (lane < 16) { redS[wave][col] = s; redQ[wave][col] = qq; }
    }
    __syncthreads();
    if (t < 64) {
        pS[(size_t)blockIdx.x * 64 + t] = redS[0][t] + redS[1][t] + redS[2][t] + redS[3][t];
        pQ[(size_t)blockIdx.x * 64 + t] = redQ[0][t] + redQ[1][t] + redQ[2][t] + redQ[3][t];
    }
}

// ===== final: sigmoid(relu(bn(z2)) @ W3 + b3), bf16 z2, BN computed inline =====
__global__ __launch_bounds__(64) void final_kernel(
    const u16* __restrict__ z2,
    const float* __restrict__ sum2, const float* __restrict__ sq2,
    const float* __restrict__ g2, const float* __restrict__ be2,
    const float* __restrict__ W3, const float* __restrict__ b3, float* __restrict__ out)
{
    __shared__ float sh[64][65];
    __shared__ float sw[64];
    int t = threadIdx.x; // 64
    float mu = sum2[t] * (1.f / (float)NP);
    float var = sq2[t] * (1.f / (float)NP) - mu * mu;
    float sc = g2[t] * rsqrtf(var + 1e-5f);
    float sh2 = be2[t] - mu * sc;
    size_t row0 = (size_t)blockIdx.x * 64;
    sw[t] = W3[t];
    for (int j = 0; j < 64; ++j) {
        float v = bf2f(z2[(row0 + j) * 64 + t]) * sc + sh2;
        sh[j][t] = v > 0.f ? v : 0.f;
    }
    __syncthreads();
    float acc = b3[0];
#pragma unroll 16
    for (int k = 0; k < 64; ++k) acc = fmaf(sh[t][k], sw[k], acc);
    out[row0 + t] = 1.f / (1.f + __expf(-acc));
}

extern "C" void kernel_launch(void* const* d_in, const int* in_sizes, int n_in,
                              void* d_out, int out_size, void* d_ws, size_t ws_size,
                              hipStream_t stream) {
    const float* x_c      = (const float*)d_in[0];
    const float* x_p      = (const float*)d_in[1];
    const int*   e_src_cp = (const int*)d_in[2];
    const int*   e_dst_cp = (const int*)d_in[3];
    const int*   e_src_pp = (const int*)d_in[4];
    const int*   e_dst_pp = (const int*)d_in[5];
    const float* W_c      = (const float*)d_in[6];
    const float* b_c      = (const float*)d_in[7];
    const float* W_p      = (const float*)d_in[8];
    const float* b_p      = (const float*)d_in[9];
    const float* a_src_cp = (const float*)d_in[10];
    const float* a_dst_cp = (const float*)d_in[11];
    const float* a_src_pp = (const float*)d_in[12];
    const float* a_dst_pp = (const float*)d_in[13];
    const float* Wk       = (const float*)d_in[14];
    const float* bk       = (const float*)d_in[15];
    const float* q_sem    = (const float*)d_in[16];
    const float* W1       = (const float*)d_in[17];
    const float* b1       = (const float*)d_in[18];
    const float* g1       = (const float*)d_in[19];
    const float* be1      = (const float*)d_in[20];
    const float* W2       = (const float*)d_in[21];
    const float* b2       = (const float*)d_in[22];
    const float* g2       = (const float*)d_in[23];
    const float* be2      = (const float*)d_in[24];
    const float* W3       = (const float*)d_in[25];
    const float* b3       = (const float*)d_in[26];

    // ---- byte-offset workspace layout (extent 211,208,448 B; 212,809,472 proven OK) ----
    char* ws = (char*)d_ws;
    u16*   h_p    = (u16*)  (ws +          0);  // 51,200,000
    u16*   h_c    = (u16*)  (ws +  51200000);   // 25,600,000
    float* al_c   = (float*)(ws +  76800000);   //  3,200,000
    float* al_dcp = (float*)(ws +  80000000);   //  6,400,000
    float* al_spp = (float*)(ws +  86400000);
    float* al_dpp = (float*)(ws +  92800000);
    int*   row_ptr= (int*)  (ws +  99200000);   // (NN2+1)*4 padded -> 100,800,256
    int*   perm   = (int*)  (ws + 100800256);   // 2NE*4 -> 108,800,256
    u64*   pairs  = (u64*)  (ws + 108800256);   // 2NE*8 -> 124,800,256 [dead after bsort]
    int*   bcnt   = (int*)  (ws + 124800256);   // 392*4
    int*   bbase  = (int*)  (ws + 124801856);   // 392*4
    int*   bcur   = (int*)  (ws + 124803456);   // 392*4
    u16*   r_pp   = (u16*)  (ws + 108800256);   // NP*128 bf16 (overlays pairs+bmeta, dead)
    u16*   r_cp   = (u16*)  (ws + 160000256);   // NP*128 bf16 -> 211,200,256
    float* small  = (float*)(ws + 211200256);   // 8192

    // overlays on CSR region (dead after gather2):
    float* semPart= (float*)(ws +  99200000);   // 3,200,000 (dead before mlp2)
    float* statS  = (float*)(ws + 102400000);   // 1,600,000
    float* statQ  = (float*)(ws + 104000000);   // 1,600,000

    float* vsum   = small;        // 2
    float* sum1   = small + 128;  // 128
    float* sq1    = small + 256;  // 128
    float* sum2   = small + 384;  // 64
    float* sq2    = small + 448;  // 64

    // aliases over dead regions
    u16*   z1 = h_p;                   // bf16 NP*128 at [0,51.2M): h_p dead after gather
    u16*   z2 = (u16*)(ws + 51200000); // bf16 NP*64 = 25.6MB at [51.2M,76.8M): h_c dead after gather

    hipMemsetAsync(small, 0, 8192, stream);
    hipMemsetAsync(bcnt, 0, 1600, stream);

    // projections (MFMA) with fused per-head logits
    {
        dim3 g(NP / 64, 2);
        proj_both<<<g, 256, 0, stream>>>(x_c, W_c, b_c, x_p, W_p, b_p, h_c, h_p,
                                         a_src_cp, a_dst_cp, a_src_pp, a_dst_pp,
                                         al_c, al_dcp, al_spp, al_dpp);
    }

    // ---- bucketed CSR over both metapaths ----
    bhist<<<NBLK_E, 256, 0, stream>>>(e_dst_pp, e_dst_cp, bcnt);
    bscan<<<1, 512, 0, stream>>>(bcnt, bbase, bcur, row_ptr);
    bplace<<<NBLK_E, 256, 0, stream>>>(e_src_pp, e_dst_pp, e_src_cp, e_dst_cp, bcur, pairs);
    bsort<<<NBUK, 256, 0, stream>>>(pairs, bbase, row_ptr, perm);

    gather2<<<NN2 / 16, 256, 0, stream>>>(row_ptr, perm,
                                          al_spp, al_dpp, al_c, al_dcp,
                                          h_p, h_c, r_pp, r_cp);

    // semantic attention
    {
        dim3 gs(NP / 64, 2);
        sem_mfma<<<gs, 256, 0, stream>>>(r_cp, r_pp, Wk, bk, semPart);
    }
    sem_dot<<<32, 256, 0, stream>>>(semPart, q_sem, vsum);

    // MLP + BN
    mlp1_mfma<<<NP / 64, 256, 0, stream>>>(r_cp, r_pp, vsum, W1, b1, z1, statS, statQ);
    stat_reduce<<<25, 256, 0, stream>>>(statS, statQ, sum1, sq1, 128);
    mlp2_mfma<<<NP / 64, 256, 0, stream>>>(z1, sum1, sq1, g1, be1, W2, b2, z2, statS, statQ);
    stat_reduce<<<25, 256, 0, stream>>>(statS, statQ, sum2, sq2, 64);
    final_kernel<<<NP / 64, 64, 0, stream>>>(z2, sum2, sq2, g2, be2, W3, b3, (float*)d_out);
}

// Round 14
// 394.569 us; speedup vs baseline: 1.4674x; 1.1919x over previous
//
#include <hip/hip_runtime.h>
#include <hip/hip_bf16.h>

#define NC 100000
#define NP 200000
#define NE 1000000
#define NN2 (2 * NP)      // combined dst-node space (pp then cp)
#define NBUK 391          // ceil(NN2/1024)
#define ECHUNK 8192
#define NBLK_E 245        // ceil(2*NE/8192)
#define NTILE 3125        // NP/64
#define SEMB 782          // ceil(NTILE/4)

typedef unsigned short u16;
typedef unsigned int u32;
typedef unsigned long long u64;
typedef __attribute__((ext_vector_type(8))) short short8v;  // 8 bf16 (4 VGPRs)
typedef __attribute__((ext_vector_type(4))) float f32x4;

__device__ __forceinline__ float bf2f(u16 v) {
    union { u32 u; float f; } c; c.u = ((u32)v) << 16; return c.f;
}
__device__ __forceinline__ u16 f2bf(float f) {
    union { float f; u32 u; } c; c.f = f;
    u32 u = c.u;
    return (u16)((u + 0x7FFFu + ((u >> 16) & 1u)) >> 16); // RNE
}
__device__ __forceinline__ u32 pack2(float lo, float hi) {
    return (u32)f2bf(lo) | ((u32)f2bf(hi) << 16);
}
__device__ __forceinline__ float tanh_fast(float x) {
    return 1.f - 2.f / (__expf(2.f * x) + 1.f);
}
__device__ __forceinline__ short8v mk8(u32 a, u32 b, u32 c, u32 d) {
    union { u32 u[4]; short8v v; } t; t.u[0] = a; t.u[1] = b; t.u[2] = c; t.u[3] = d; return t.v;
}

// ========== proj (both types): h = bf16(x @ W + b) via MFMA, + fused logits ==========
__global__ __launch_bounds__(256) void proj_both(
    const float* __restrict__ x_c, const float* __restrict__ W_c, const float* __restrict__ b_c,
    const float* __restrict__ x_p, const float* __restrict__ W_p, const float* __restrict__ b_p,
    u16* __restrict__ out_c, u16* __restrict__ out_p,
    const float* __restrict__ a_cp_s,
    const float* __restrict__ a_cp_d, const float* __restrict__ a_pp_s,
    const float* __restrict__ a_pp_d,
    float* __restrict__ al_c, float* __restrict__ al_dcp,
    float* __restrict__ al_spp, float* __restrict__ al_dpp)
{
    const float* x; const float* W; const float* b; u16* h; int N;
    int py = blockIdx.y;
    if (py == 0) { x = x_c; W = W_c; b = b_c; h = out_c; N = NC; }
    else         { x = x_p; W = W_p; b = b_p; h = out_p; N = NP; }
    size_t row0 = (size_t)blockIdx.x * 64;
    if (row0 >= (size_t)N) return;
    __shared__ alignas(16) u16 sBT[128 * 72];
    __shared__ alignas(16) u16 sA[64 * 72];
    __shared__ alignas(16) u16 hTile[64 * 136];
    __shared__ float aV[3][128];
    int t = threadIdx.x;
    if (t < 128) {
        aV[0][t] = py ? a_cp_d[t] : a_cp_s[t];
        aV[1][t] = py ? a_pp_s[t] : 0.f;
        aV[2][t] = py ? a_pp_d[t] : 0.f;
    }
    for (int i = t; i < 128 * 8; i += 256) {
        int n = i & 127, kb = i >> 7;
        u32 p[4];
#pragma unroll
        for (int j = 0; j < 4; ++j)
            p[j] = pack2(W[(kb * 8 + 2 * j) * 128 + n], W[(kb * 8 + 2 * j + 1) * 128 + n]);
        *(uint4*)(&sBT[n * 72 + kb * 8]) = make_uint4(p[0], p[1], p[2], p[3]);
    }
    for (int i = t; i < 64 * 8; i += 256) {
        int r = i >> 3, c8 = (i & 7) * 8;
        u32 p[4];
        if (row0 + r < (size_t)N) {
            const float* src = x + (row0 + r) * 64 + c8;
            float4 v0 = *(const float4*)src;
            float4 v1 = *(const float4*)(src + 4);
            p[0] = pack2(v0.x, v0.y); p[1] = pack2(v0.z, v0.w);
            p[2] = pack2(v1.x, v1.y); p[3] = pack2(v1.z, v1.w);
        } else { p[0] = p[1] = p[2] = p[3] = 0; }
        *(uint4*)(&sA[r * 72 + c8]) = make_uint4(p[0], p[1], p[2], p[3]);
    }
    __syncthreads();
    int wave = t >> 6, lane = t & 63;
    int fr = lane & 15, fq = lane >> 4;
    const u16* pA = sA + (wave * 16 + fr) * 72 + fq * 8;
    const u16* pB = sBT + fr * 72 + fq * 8;
    f32x4 acc[8];
#pragma unroll
    for (int nt = 0; nt < 8; ++nt) { float bb = b[nt * 16 + fr]; acc[nt] = (f32x4){bb, bb, bb, bb}; }
#pragma unroll
    for (int ks = 0; ks < 2; ++ks) {
        short8v a = *(const short8v*)(pA + ks * 32);
#pragma unroll
        for (int nt = 0; nt < 8; ++nt) {
            short8v bv = *(const short8v*)(pB + nt * 16 * 72 + ks * 32);
            acc[nt] = __builtin_amdgcn_mfma_f32_16x16x32_bf16(a, bv, acc[nt], 0, 0, 0);
        }
    }
    size_t rbase = row0 + wave * 16 + fq * 4;
    int lrow0 = wave * 16 + fq * 4;
#pragma unroll
    for (int nt = 0; nt < 8; ++nt) {
        int col = nt * 16 + fr;
#pragma unroll
        for (int rg = 0; rg < 4; ++rg) {
            size_t rr = rbase + rg;
            u16 hv = f2bf(acc[nt][rg]);
            if (rr < (size_t)N) h[rr * 128 + col] = hv;
            hTile[(lrow0 + rg) * 136 + col] = hv;
        }
    }
    __syncthreads();
    // fused per-head logits from the LDS h tile
    int row = t >> 2;
    size_t grow = row0 + row;
    if (grow < (size_t)N) {
#pragma unroll
        for (int hd = t & 3; hd < 8; hd += 4) {
            const u16* hp = &hTile[row * 136 + hd * 16];
            uint4 u0_ = *(const uint4*)hp;
            uint4 u1_ = *(const uint4*)(hp + 8);
            u32 uu[8] = {u0_.x, u0_.y, u0_.z, u0_.w, u1_.x, u1_.y, u1_.z, u1_.w};
            float p0 = 0.f, p1 = 0.f, p2 = 0.f;
#pragma unroll
            for (int j = 0; j < 8; ++j) {
                float lo = bf2f((u16)(uu[j] & 0xFFFFu));
                float hi = bf2f((u16)(uu[j] >> 16));
                int c = hd * 16 + 2 * j;
                p0 += lo * aV[0][c] + hi * aV[0][c + 1];
                p1 += lo * aV[1][c] + hi * aV[1][c + 1];
                p2 += lo * aV[2][c] + hi * aV[2][c + 1];
            }
            if (py == 0) {
                al_c[grow * 8 + hd] = p0;
            } else {
                al_dcp[grow * 8 + hd] = p0;
                al_spp[grow * 8 + hd] = p1;
                al_dpp[grow * 8 + hd] = p2;
            }
        }
    }
}

// ================= bucketed CSR build =================
__global__ __launch_bounds__(256) void bhist(const int* __restrict__ dpp, const int* __restrict__ dcp,
                                             int* __restrict__ bcnt)
{
    __shared__ int h[NBUK];
    int t = threadIdx.x;
    for (int i = t; i < NBUK; i += 256) h[i] = 0;
    __syncthreads();
    int base = blockIdx.x * ECHUNK;
    int lim = min(ECHUNK, 2 * NE - base);
    for (int i = t; i < lim; i += 256) {
        int e = base + i;
        int d2 = (e < NE) ? dpp[e] : NP + dcp[e - NE];
        atomicAdd(&h[d2 >> 10], 1);
    }
    __syncthreads();
    for (int i = t; i < NBUK; i += 256) if (h[i]) atomicAdd(&bcnt[i], h[i]);
}

__global__ __launch_bounds__(512) void bscan(const int* __restrict__ bcnt, int* __restrict__ bbase,
                                             int* __restrict__ bcur, int* __restrict__ row_ptr)
{
    __shared__ int s[512];
    int t = threadIdx.x;
    int v = (t < NBUK) ? bcnt[t] : 0;
    s[t] = v;
    __syncthreads();
    for (int off = 1; off < 512; off <<= 1) {
        int x = (t >= off) ? s[t - off] : 0;
        __syncthreads();
        s[t] += x;
        __syncthreads();
    }
    if (t < NBUK) { bbase[t] = s[t] - v; bcur[t] = s[t] - v; }
    if (t == 0) { bbase[NBUK] = 2 * NE; row_ptr[NN2] = 2 * NE; }
}

__global__ __launch_bounds__(256) void bplace(
    const int* __restrict__ spp, const int* __restrict__ dpp,
    const int* __restrict__ scp, const int* __restrict__ dcp,
    int* __restrict__ bcur, u64* __restrict__ pairs)
{
    __shared__ int h[NBUK];
    __shared__ int rk[NBUK];
    int t = threadIdx.x;
    for (int i = t; i < NBUK; i += 256) h[i] = 0;
    __syncthreads();
    int base = blockIdx.x * ECHUNK;
    int lim = min(ECHUNK, 2 * NE - base);
    for (int i = t; i < lim; i += 256) {
        int e = base + i;
        int d2 = (e < NE) ? dpp[e] : NP + dcp[e - NE];
        atomicAdd(&h[d2 >> 10], 1);
    }
    __syncthreads();
    for (int i = t; i < NBUK; i += 256) {
        int c = h[i];
        h[i] = c ? atomicAdd(&bcur[i], c) : 0;
        rk[i] = 0;
    }
    __syncthreads();
    for (int i = t; i < lim; i += 256) {
        int e = base + i;
        int d2, src;
        if (e < NE) { d2 = dpp[e];      src = spp[e]; }
        else        { d2 = NP + dcp[e - NE]; src = scp[e - NE]; }
        int b = d2 >> 10;
        int r = atomicAdd(&rk[b], 1);
        pairs[h[b] + r] = ((u64)(u32)d2 << 32) | (u32)src;
    }
}

__global__ __launch_bounds__(256) void bsort(
    const u64* __restrict__ pairs, const int* __restrict__ bbase,
    int* __restrict__ row_ptr, int* __restrict__ perm)
{
    __shared__ int cnt[1024];
    __shared__ int sc[256];
    int b = blockIdx.x, t = threadIdx.x;
    int beg = bbase[b], end = bbase[b + 1];
    for (int i = t; i < 1024; i += 256) cnt[i] = 0;
    __syncthreads();
    for (int i = beg + t; i < end; i += 256) {
        int d2 = (int)(pairs[i] >> 32);
        atomicAdd(&cnt[d2 & 1023], 1);
    }
    __syncthreads();
    int b4 = t * 4;
    int c0 = cnt[b4], c1 = cnt[b4 + 1], c2 = cnt[b4 + 2], c3 = cnt[b4 + 3];
    int s = c0 + c1 + c2 + c3;
    sc[t] = s;
    __syncthreads();
    for (int off = 1; off < 256; off <<= 1) {
        int x = (t >= off) ? sc[t - off] : 0;
        __syncthreads();
        sc[t] += x;
        __syncthreads();
    }
    int run = sc[t] - s;
    int o0 = run, o1 = run + c0, o2 = o1 + c1, o3 = o2 + c2;
    cnt[b4] = o0; cnt[b4 + 1] = o1; cnt[b4 + 2] = o2; cnt[b4 + 3] = o3;
    int gidx = b * 1024 + b4;
    if (gidx     < NN2) row_ptr[gidx]     = beg + o0;
    if (gidx + 1 < NN2) row_ptr[gidx + 1] = beg + o1;
    if (gidx + 2 < NN2) row_ptr[gidx + 2] = beg + o2;
    if (gidx + 3 < NN2) row_ptr[gidx + 3] = beg + o3;
    __syncthreads();
    for (int i = beg + t; i < end; i += 256) {
        u64 p = pairs[i];
        int d2 = (int)(p >> 32);
        int r = atomicAdd(&cnt[d2 & 1023], 1);
        perm[beg + r] = (int)(p & 0xFFFFFFFFull);
    }
}

// ===== gather (proven single-chain): 16 lanes/dst, perm preload + 1-deep pipeline =====
__global__ __launch_bounds__(256) void gather2(
    const int* __restrict__ row_ptr, const int* __restrict__ perm,
    const float* __restrict__ als_pp, const float* __restrict__ ald_pp,
    const float* __restrict__ als_cp, const float* __restrict__ ald_cp,
    const u16* __restrict__ h_p, const u16* __restrict__ h_c,
    u16* __restrict__ r_pp, u16* __restrict__ r_cp)
{
    int d2 = blockIdx.x * 16 + (threadIdx.x >> 4);
    int lane = threadIdx.x & 63;
    int l16 = lane & 15;
    int grp = lane & 48;
    int head = l16 >> 1;
    const float* als; const float* ald; const u16* hs; u16* out; int d;
    if (d2 < NP) { d = d2;      als = als_pp; ald = ald_pp; hs = h_p; out = r_pp; }
    else         { d = d2 - NP; als = als_cp; ald = ald_cp; hs = h_c; out = r_cp; }
    int beg = row_ptr[d2], end = row_ptr[d2 + 1];
    int n = end - beg;
    float ald_h = ald[(size_t)d * 8 + head];
    float dsum = 0.f;
    float acc[8] = {0.f, 0.f, 0.f, 0.f, 0.f, 0.f, 0.f, 0.f};
    for (int base = 0; base < n; base += 16) {
        int cnt = min(16, n - base);
        int my = (base + l16 < n) ? perm[beg + base + l16] : 0;
        int src = __shfl(my, grp, 64);
        float a_next = als[(size_t)src * 8 + head];
        uint4 hv_next = *(const uint4*)(hs + (size_t)src * 128 + l16 * 8);
        for (int j = 0; j < cnt; ++j) {
            float a_cur = a_next;
            uint4 hv = hv_next;
            if (j + 1 < cnt) {
                int s2 = __shfl(my, grp + j + 1, 64);
                a_next = als[(size_t)s2 * 8 + head];
                hv_next = *(const uint4*)(hs + (size_t)s2 * 128 + l16 * 8);
            }
            float a = a_cur + ald_h;
            a = a >= 0.f ? a : 0.2f * a;
            float w = __expf(a);
            dsum += w;
            u32 uu[4] = {hv.x, hv.y, hv.z, hv.w};
#pragma unroll
            for (int q = 0; q < 4; ++q) {
                acc[2 * q]     = fmaf(bf2f((u16)(uu[q] & 0xFFFFu)), w, acc[2 * q]);
                acc[2 * q + 1] = fmaf(bf2f((u16)(uu[q] >> 16)),     w, acc[2 * q + 1]);
            }
        }
    }
    float inv = 1.f / (dsum + 1e-16f);
    uint4 o;
    o.x = pack2(fmaxf(acc[0] * inv, 0.f), fmaxf(acc[1] * inv, 0.f));
    o.y = pack2(fmaxf(acc[2] * inv, 0.f), fmaxf(acc[3] * inv, 0.f));
    o.z = pack2(fmaxf(acc[4] * inv, 0.f), fmaxf(acc[5] * inv, 0.f));
    o.w = pack2(fmaxf(acc[6] * inv, 0.f), fmaxf(acc[7] * inv, 0.f));
    *(uint4*)(out + (size_t)d * 128 + l16 * 8) = o;
}

// ===== sem: B(Wk) in LDS once, 4 row-tiles per block, A direct-from-global =====
__global__ __launch_bounds__(256) void sem_mfma(
    const u16* __restrict__ r0, const u16* __restrict__ r1,
    const float* __restrict__ Wk, const float* __restrict__ bk,
    float* __restrict__ part)   // [2][SEMB][128]
{
    __shared__ alignas(16) u16 sBT[128 * 136];
    __shared__ float red[4][128];
    int t = threadIdx.x;
    const u16* src = blockIdx.y ? r1 : r0;
    for (int i = t; i < 128 * 16; i += 256) {
        int n = i & 127, kb = i >> 7;
        u32 p[4];
#pragma unroll
        for (int j = 0; j < 4; ++j)
            p[j] = pack2(Wk[(kb * 8 + 2 * j) * 128 + n], Wk[(kb * 8 + 2 * j + 1) * 128 + n]);
        *(uint4*)(&sBT[n * 136 + kb * 8]) = make_uint4(p[0], p[1], p[2], p[3]);
    }
    __syncthreads();
    int wave = t >> 6, lane = t & 63;
    int fr = lane & 15, fq = lane >> 4;
    const u16* pB = sBT + fr * 136 + fq * 8;
    float bias = bk[fr];      // per-nt bias loaded below (bk[nt*16+fr])
    float sacc[8] = {0.f, 0.f, 0.f, 0.f, 0.f, 0.f, 0.f, 0.f};
    float bkv[8];
#pragma unroll
    for (int nt = 0; nt < 8; ++nt) bkv[nt] = bk[nt * 16 + fr];
    (void)bias;
    for (int ti = 0; ti < 4; ++ti) {
        int tile = blockIdx.x * 4 + ti;
        if (tile >= NTILE) break;
        size_t arow = (size_t)tile * 64 + wave * 16 + fr;
        const u16* ap = src + arow * 128 + fq * 8;
        short8v afr[4];
#pragma unroll
        for (int ks = 0; ks < 4; ++ks) afr[ks] = *(const short8v*)(ap + ks * 32);
        f32x4 acc[8];
#pragma unroll
        for (int nt = 0; nt < 8; ++nt) acc[nt] = (f32x4){bkv[nt], bkv[nt], bkv[nt], bkv[nt]};
#pragma unroll
        for (int ks = 0; ks < 4; ++ks) {
#pragma unroll
            for (int nt = 0; nt < 8; ++nt) {
                short8v bv = *(const short8v*)(pB + nt * 16 * 136 + ks * 32);
                acc[nt] = __builtin_amdgcn_mfma_f32_16x16x32_bf16(afr[ks], bv, acc[nt], 0, 0, 0);
            }
        }
#pragma unroll
        for (int nt = 0; nt < 8; ++nt) {
            f32x4 v = acc[nt];
            sacc[nt] += tanh_fast(v[0]) + tanh_fast(v[1]) + tanh_fast(v[2]) + tanh_fast(v[3]);
        }
    }
#pragma unroll
    for (int nt = 0; nt < 8; ++nt) {
        float s = sacc[nt];
        s += __shfl_xor(s, 16, 64);
        s += __shfl_xor(s, 32, 64);
        if (lane < 16) red[wave][nt * 16 + lane] = s;
    }
    __syncthreads();
    if (t < 128) {
        float s = red[0][t] + red[1][t] + red[2][t] + red[3][t];
        part[((size_t)blockIdx.y * SEMB + blockIdx.x) * 128 + t] = s;
    }
}

// ================= sem partial-dot over [2][SEMB][128] =================
__global__ __launch_bounds__(256) void sem_dot(const float* __restrict__ part,
                                               const float* __restrict__ q, float* __restrict__ vsum)
{
    __shared__ float sq_[128];
    __shared__ float red[256];
    int t = threadIdx.x;
    if (t < 128) sq_[t] = q[t];
    __syncthreads();
    int c = t & 127, m = t >> 7;
    int i0 = blockIdx.x * 25;
    int i1 = i0 + 25; if (i1 > SEMB) i1 = SEMB;
    float acc = 0.f;
    for (int i = i0; i < i1; ++i)
        acc += part[((size_t)m * SEMB + i) * 128 + c] * sq_[c];
    red[t] = acc;
    __syncthreads();
    for (int off = 64; off >= 1; off >>= 1) {
        if ((t & 127) < off) red[t] += red[t + off];
        __syncthreads();
    }
    if ((t & 127) == 0) atomicAdd(&vsum[m], red[t]);
}

// ==== MLP1: B(W1) in LDS once, 4 tiles/block, A = (a0*r_cp+a1*r_pp) in-register ====
__global__ __launch_bounds__(256) void mlp1_mfma(
    const u16* __restrict__ rcp, const u16* __restrict__ rpp, const float* __restrict__ vsum,
    const float* __restrict__ W1, const float* __restrict__ b1,
    u16* __restrict__ z1, float* __restrict__ pS, float* __restrict__ pQ)
{
    __shared__ alignas(16) u16 sBT[128 * 136];
    __shared__ float redS[4][128];
    __shared__ float redQ[4][128];
    int t = threadIdx.x;
    float v0 = vsum[0] * (1.f / (float)NP), v1 = vsum[1] * (1.f / (float)NP);
    float mx = fmaxf(v0, v1);
    float e0 = __expf(v0 - mx), e1 = __expf(v1 - mx);
    float is = 1.f / (e0 + e1);
    float a0 = e0 * is, a1 = e1 * is;
    for (int i = t; i < 128 * 16; i += 256) {
        int n = i & 127, kb = i >> 7;
        u32 p[4];
#pragma unroll
        for (int j = 0; j < 4; ++j)
            p[j] = pack2(W1[(kb * 8 + 2 * j) * 128 + n], W1[(kb * 8 + 2 * j + 1) * 128 + n]);
        *(uint4*)(&sBT[n * 136 + kb * 8]) = make_uint4(p[0], p[1], p[2], p[3]);
    }
    __syncthreads();
    int wave = t >> 6, lane = t & 63;
    int fr = lane & 15, fq = lane >> 4;
    const u16* pB = sBT + fr * 136 + fq * 8;
    float b1v[8];
#pragma unroll
    for (int nt = 0; nt < 8; ++nt) b1v[nt] = b1[nt * 16 + fr];
    float saccS[8] = {0.f, 0.f, 0.f, 0.f, 0.f, 0.f, 0.f, 0.f};
    float saccQ[8] = {0.f, 0.f, 0.f, 0.f, 0.f, 0.f, 0.f, 0.f};
    for (int ti = 0; ti < 4; ++ti) {
        int tile = blockIdx.x * 4 + ti;
        if (tile >= NTILE) break;
        size_t row0 = (size_t)tile * 64;
        size_t arow = row0 + wave * 16 + fr;
        const u16* rc = rcp + arow * 128 + fq * 8;
        const u16* rp = rpp + arow * 128 + fq * 8;
        f32x4 acc[8];
#pragma unroll
        for (int nt = 0; nt < 8; ++nt) acc[nt] = (f32x4){b1v[nt], b1v[nt], b1v[nt], b1v[nt]};
#pragma unroll
        for (int ks = 0; ks < 4; ++ks) {
            uint4 uc = *(const uint4*)(rc + ks * 32);
            uint4 up = *(const uint4*)(rp + ks * 32);
            u32 cu[4] = {uc.x, uc.y, uc.z, uc.w};
            u32 pu[4] = {up.x, up.y, up.z, up.w};
            u32 pw[4];
#pragma unroll
            for (int j = 0; j < 4; ++j) {
                float lo = a0 * bf2f((u16)(cu[j] & 0xFFFFu)) + a1 * bf2f((u16)(pu[j] & 0xFFFFu));
                float hi = a0 * bf2f((u16)(cu[j] >> 16))     + a1 * bf2f((u16)(pu[j] >> 16));
                pw[j] = pack2(lo, hi);
            }
            short8v a = mk8(pw[0], pw[1], pw[2], pw[3]);
#pragma unroll
            for (int nt = 0; nt < 8; ++nt) {
                short8v bv = *(const short8v*)(pB + nt * 16 * 136 + ks * 32);
                acc[nt] = __builtin_amdgcn_mfma_f32_16x16x32_bf16(a, bv, acc[nt], 0, 0, 0);
            }
        }
        size_t rbase = row0 + wave * 16 + fq * 4;
#pragma unroll
        for (int nt = 0; nt < 8; ++nt) {
            f32x4 v = acc[nt];
            int col = nt * 16 + fr;
#pragma unroll
            for (int rg = 0; rg < 4; ++rg)
                z1[(rbase + rg) * 128 + col] = f2bf(v[rg]);
            saccS[nt] += v[0] + v[1] + v[2] + v[3];
            saccQ[nt] += v[0] * v[0] + v[1] * v[1] + v[2] * v[2] + v[3] * v[3];
        }
    }
#pragma unroll
    for (int nt = 0; nt < 8; ++nt) {
        float s = saccS[nt], qq = saccQ[nt];
        s += __shfl_xor(s, 16, 64);  s += __shfl_xor(s, 32, 64);
        qq += __shfl_xor(qq, 16, 64); qq += __shfl_xor(qq, 32, 64);
        if (lane < 16) { redS[wave][nt * 16 + lane] = s; redQ[wave][nt * 16 + lane] = qq; }
    }
    __syncthreads();
    if (t < 128) {
        pS[(size_t)blockIdx.x * 128 + t] = redS[0][t] + redS[1][t] + redS[2][t] + redS[3][t];
        pQ[(size_t)blockIdx.x * 128 + t] = redQ[0][t] + redQ[1][t] + redQ[2][t] + redQ[3][t];
    }
}

// ================= reduce BN partials [SEMB][C] -> sum/sq =================
__global__ __launch_bounds__(256) void stat_reduce(
    const float* __restrict__ pS, const float* __restrict__ pQ,
    float* __restrict__ sum, float* __restrict__ sq, int C)
{
    __shared__ float redS[256], redQ[256];
    int t = threadIdx.x;
    int c = t & (C - 1);
    int sub = t / C;
    int stride = 256 / C;
    int i0 = blockIdx.x * 32, i1 = i0 + 32;
    if (i1 > SEMB) i1 = SEMB;
    float s = 0.f, q = 0.f;
    for (int i = i0 + sub; i < i1; i += stride) {
        s += pS[(size_t)i * C + c];
        q += pQ[(size_t)i * C + c];
    }
    redS[t] = s; redQ[t] = q;
    __syncthreads();
    if (t < C) {
        for (int k = 1; k < stride; ++k) { s += redS[t + k * C]; q += redQ[t + k * C]; }
        atomicAdd(&sum[c], s);
        atomicAdd(&sq[c], q);
    }
}

// ===== MLP2: B(W2) in LDS once, 4 tiles/block, A = relu(bn(z1)) in-register =====
__global__ __launch_bounds__(256) void mlp2_mfma(
    const u16* __restrict__ z1,
    const float* __restrict__ sum1, const float* __restrict__ sq1,
    const float* __restrict__ g1, const float* __restrict__ be1,
    const float* __restrict__ W2, const float* __restrict__ b2,
    u16* __restrict__ z2, float* __restrict__ pS, float* __restrict__ pQ)
{
    __shared__ alignas(16) u16 sBT[64 * 136];
    __shared__ float sSc[128], sSh[128];
    __shared__ float redS[4][64], redQ[4][64];
    int t = threadIdx.x;
    if (t < 128) {
        float mu = sum1[t] * (1.f / (float)NP);
        float var = sq1[t] * (1.f / (float)NP) - mu * mu;
        float sc = g1[t] * rsqrtf(var + 1e-5f);
        sSc[t] = sc;
        sSh[t] = be1[t] - mu * sc;
    }
    for (int i = t; i < 64 * 16; i += 256) {
        int n = i & 63, kb = i >> 6;
        u32 p[4];
#pragma unroll
        for (int j = 0; j < 4; ++j)
            p[j] = pack2(W2[(kb * 8 + 2 * j) * 64 + n], W2[(kb * 8 + 2 * j + 1) * 64 + n]);
        *(uint4*)(&sBT[n * 136 + kb * 8]) = make_uint4(p[0], p[1], p[2], p[3]);
    }
    __syncthreads();
    int wave = t >> 6, lane = t & 63;
    int fr = lane & 15, fq = lane >> 4;
    const u16* pB = sBT + fr * 136 + fq * 8;
    float b2v[4];
#pragma unroll
    for (int nt = 0; nt < 4; ++nt) b2v[nt] = b2[nt * 16 + fr];
    float sc_[8], sh_[8];
#pragma unroll
    for (int ks = 0; ks < 4; ++ks) {
        int c0 = ks * 32 + fq * 8;
        // cached per-k-slice scale/shift pairs are re-read from LDS below (cheap)
        (void)c0;
    }
    float saccS[4] = {0.f, 0.f, 0.f, 0.f};
    float saccQ[4] = {0.f, 0.f, 0.f, 0.f};
    (void)sc_; (void)sh_;
    for (int ti = 0; ti < 4; ++ti) {
        int tile = blockIdx.x * 4 + ti;
        if (tile >= NTILE) break;
        size_t row0 = (size_t)tile * 64;
        size_t arow = row0 + wave * 16 + fr;
        const u16* zp = z1 + arow * 128 + fq * 8;
        f32x4 acc[4];
#pragma unroll
        for (int nt = 0; nt < 4; ++nt) acc[nt] = (f32x4){b2v[nt], b2v[nt], b2v[nt], b2v[nt]};
#pragma unroll
        for (int ks = 0; ks < 4; ++ks) {
            uint4 uz = *(const uint4*)(zp + ks * 32);
            u32 zu[4] = {uz.x, uz.y, uz.z, uz.w};
            u32 pw[4];
            int c0 = ks * 32 + fq * 8;
#pragma unroll
            for (int j = 0; j < 4; ++j) {
                int c = c0 + 2 * j;
                float lo = fmaxf(bf2f((u16)(zu[j] & 0xFFFFu)) * sSc[c] + sSh[c], 0.f);
                float hi = fmaxf(bf2f((u16)(zu[j] >> 16)) * sSc[c + 1] + sSh[c + 1], 0.f);
                pw[j] = pack2(lo, hi);
            }
            short8v a = mk8(pw[0], pw[1], pw[2], pw[3]);
#pragma unroll
            for (int nt = 0; nt < 4; ++nt) {
                short8v bv = *(const short8v*)(pB + nt * 16 * 136 + ks * 32);
                acc[nt] = __builtin_amdgcn_mfma_f32_16x16x32_bf16(a, bv, acc[nt], 0, 0, 0);
            }
        }
        size_t rbase = row0 + wave * 16 + fq * 4;
#pragma unroll
        for (int nt = 0; nt < 4; ++nt) {
            f32x4 v = acc[nt];
            int col = nt * 16 + fr;
#pragma unroll
            for (int rg = 0; rg < 4; ++rg)
                z2[(rbase + rg) * 64 + col] = f2bf(v[rg]);
            saccS[nt] += v[0] + v[1] + v[2] + v[3];
            saccQ[nt] += v[0] * v[0] + v[1] * v[1] + v[2] * v[2] + v[3] * v[3];
        }
    }
#pragma unroll
    for (int nt = 0; nt < 4; ++nt) {
        float s = saccS[nt], qq = saccQ[nt];
        s += __shfl_xor(s, 16, 64);  s += __shfl_xor(s, 32, 64);
        qq += __shfl_xor(qq, 16, 64); qq += __shfl_xor(qq, 32, 64);
        if (lane < 16) { redS[wave][nt * 16 + lane] = s; redQ[wave][nt * 16 + lane] = qq; }
    }
    __syncthreads();
    if (t < 64) {
        pS[(size_t)blockIdx.x * 64 + t] = redS[0][t] + redS[1][t] + redS[2][t] + redS[3][t];
        pQ[(size_t)blockIdx.x * 64 + t] = redQ[0][t] + redQ[1][t] + redQ[2][t] + redQ[3][t];
    }
}

// ===== final: sigmoid(relu(bn(z2)) @ W3 + b3), bf16 z2, BN computed inline =====
__global__ __launch_bounds__(64) void final_kernel(
    const u16* __restrict__ z2,
    const float* __restrict__ sum2, const float* __restrict__ sq2,
    const float* __restrict__ g2, const float* __restrict__ be2,
    const float* __restrict__ W3, const float* __restrict__ b3, float* __restrict__ out)
{
    __shared__ float sh[64][65];
    __shared__ float sw[64];
    int t = threadIdx.x; // 64
    float mu = sum2[t] * (1.f / (float)NP);
    float var = sq2[t] * (1.f / (float)NP) - mu * mu;
    float sc = g2[t] * rsqrtf(var + 1e-5f);
    float sh2 = be2[t] - mu * sc;
    size_t row0 = (size_t)blockIdx.x * 64;
    sw[t] = W3[t];
    for (int j = 0; j < 64; ++j) {
        float v = bf2f(z2[(row0 + j) * 64 + t]) * sc + sh2;
        sh[j][t] = v > 0.f ? v : 0.f;
    }
    __syncthreads();
    float acc = b3[0];
#pragma unroll 16
    for (int k = 0; k < 64; ++k) acc = fmaf(sh[t][k], sw[k], acc);
    out[row0 + t] = 1.f / (1.f + __expf(-acc));
}

extern "C" void kernel_launch(void* const* d_in, const int* in_sizes, int n_in,
                              void* d_out, int out_size, void* d_ws, size_t ws_size,
                              hipStream_t stream) {
    const float* x_c      = (const float*)d_in[0];
    const float* x_p      = (const float*)d_in[1];
    const int*   e_src_cp = (const int*)d_in[2];
    const int*   e_dst_cp = (const int*)d_in[3];
    const int*   e_src_pp = (const int*)d_in[4];
    const int*   e_dst_pp = (const int*)d_in[5];
    const float* W_c      = (const float*)d_in[6];
    const float* b_c      = (const float*)d_in[7];
    const float* W_p      = (const float*)d_in[8];
    const float* b_p      = (const float*)d_in[9];
    const float* a_src_cp = (const float*)d_in[10];
    const float* a_dst_cp = (const float*)d_in[11];
    const float* a_src_pp = (const float*)d_in[12];
    const float* a_dst_pp = (const float*)d_in[13];
    const float* Wk       = (const float*)d_in[14];
    const float* bk       = (const float*)d_in[15];
    const float* q_sem    = (const float*)d_in[16];
    const float* W1       = (const float*)d_in[17];
    const float* b1       = (const float*)d_in[18];
    const float* g1       = (const float*)d_in[19];
    const float* be1      = (const float*)d_in[20];
    const float* W2       = (const float*)d_in[21];
    const float* b2       = (const float*)d_in[22];
    const float* g2       = (const float*)d_in[23];
    const float* be2      = (const float*)d_in[24];
    const float* W3       = (const float*)d_in[25];
    const float* b3       = (const float*)d_in[26];

    // ---- byte-offset workspace layout (extent 211,208,448 B; 212,809,472 proven OK) ----
    char* ws = (char*)d_ws;
    u16*   h_p    = (u16*)  (ws +          0);  // 51,200,000
    u16*   h_c    = (u16*)  (ws +  51200000);   // 25,600,000
    float* al_c   = (float*)(ws +  76800000);   //  3,200,000
    float* al_dcp = (float*)(ws +  80000000);   //  6,400,000
    float* al_spp = (float*)(ws +  86400000);
    float* al_dpp = (float*)(ws +  92800000);
    int*   row_ptr= (int*)  (ws +  99200000);   // (NN2+1)*4 padded -> 100,800,256
    int*   perm   = (int*)  (ws + 100800256);   // 2NE*4 -> 108,800,256
    u64*   pairs  = (u64*)  (ws + 108800256);   // 2NE*8 -> 124,800,256 [dead after bsort]
    int*   bcnt   = (int*)  (ws + 124800256);   // 392*4
    int*   bbase  = (int*)  (ws + 124801856);   // 392*4
    int*   bcur   = (int*)  (ws + 124803456);   // 392*4
    u16*   r_pp   = (u16*)  (ws + 108800256);   // NP*128 bf16 (overlays pairs+bmeta, dead)
    u16*   r_cp   = (u16*)  (ws + 160000256);   // NP*128 bf16 -> 211,200,256
    float* small  = (float*)(ws + 211200256);   // 8192

    // overlays on CSR region (dead after gather2):
    float* semPart= (float*)(ws +  99200000);   // 2*SEMB*128*4 = 800,768 (dead before mlp2)
    float* statS  = (float*)(ws + 102400000);   // SEMB*128*4 = 400,384
    float* statQ  = (float*)(ws + 104000000);   // 400,384

    float* vsum   = small;        // 2
    float* sum1   = small + 128;  // 128
    float* sq1    = small + 256;  // 128
    float* sum2   = small + 384;  // 64
    float* sq2    = small + 448;  // 64

    // aliases over dead regions
    u16*   z1 = h_p;                   // bf16 NP*128 at [0,51.2M): h_p dead after gather
    u16*   z2 = (u16*)(ws + 51200000); // bf16 NP*64 = 25.6MB at [51.2M,76.8M): h_c dead after gather

    hipMemsetAsync(small, 0, 8192, stream);
    hipMemsetAsync(bcnt, 0, 1600, stream);

    // projections (MFMA) with fused per-head logits
    {
        dim3 g(NP / 64, 2);
        proj_both<<<g, 256, 0, stream>>>(x_c, W_c, b_c, x_p, W_p, b_p, h_c, h_p,
                                         a_src_cp, a_dst_cp, a_src_pp, a_dst_pp,
                                         al_c, al_dcp, al_spp, al_dpp);
    }

    // ---- bucketed CSR over both metapaths ----
    bhist<<<NBLK_E, 256, 0, stream>>>(e_dst_pp, e_dst_cp, bcnt);
    bscan<<<1, 512, 0, stream>>>(bcnt, bbase, bcur, row_ptr);
    bplace<<<NBLK_E, 256, 0, stream>>>(e_src_pp, e_dst_pp, e_src_cp, e_dst_cp, bcur, pairs);
    bsort<<<NBUK, 256, 0, stream>>>(pairs, bbase, row_ptr, perm);

    gather2<<<NN2 / 16, 256, 0, stream>>>(row_ptr, perm,
                                          al_spp, al_dpp, al_c, al_dcp,
                                          h_p, h_c, r_pp, r_cp);

    // semantic attention (4 tiles/block, A direct)
    {
        dim3 gs(SEMB, 2);
        sem_mfma<<<gs, 256, 0, stream>>>(r_cp, r_pp, Wk, bk, semPart);
    }
    sem_dot<<<32, 256, 0, stream>>>(semPart, q_sem, vsum);

    // MLP + BN (4 tiles/block, A in-register)
    mlp1_mfma<<<SEMB, 256, 0, stream>>>(r_cp, r_pp, vsum, W1, b1, z1, statS, statQ);
    stat_reduce<<<25, 256, 0, stream>>>(statS, statQ, sum1, sq1, 128);
    mlp2_mfma<<<SEMB, 256, 0, stream>>>(z1, sum1, sq1, g1, be1, W2, b2, z2, statS, statQ);
    stat_reduce<<<25, 256, 0, stream>>>(statS, statQ, sum2, sq2, 64);
    final_kernel<<<NP / 64, 64, 0, stream>>>(z2, sum2, sq2, g2, be2, W3, b3, (float*)d_out);
}

// Round 15
// 366.489 us; speedup vs baseline: 1.5798x; 1.0766x over previous
//
#include <hip/hip_runtime.h>
#include <hip/hip_bf16.h>

#define NC 100000
#define NP 200000
#define NE 1000000
#define NN2 (2 * NP)      // combined dst-node space (pp then cp)
#define NBUK 391          // ceil(NN2/1024)
#define ECHUNK 8192
#define NBLK_E 245        // ceil(2*NE/8192)
#define NTILE 3125        // NP/64
#define NB8 391           // ceil(NTILE/8)
#define NBLK_PC 391       // ceil(NC/256) customer proj blocks
#define NBLK_PP 782       // ceil(NP/256) product proj blocks

typedef unsigned short u16;
typedef unsigned int u32;
typedef unsigned long long u64;
typedef __attribute__((ext_vector_type(8))) short short8v;  // 8 bf16 (4 VGPRs)
typedef __attribute__((ext_vector_type(4))) float f32x4;

__device__ __forceinline__ float bf2f(u16 v) {
    union { u32 u; float f; } c; c.u = ((u32)v) << 16; return c.f;
}
__device__ __forceinline__ u16 f2bf(float f) {
    union { float f; u32 u; } c; c.f = f;
    u32 u = c.u;
    return (u16)((u + 0x7FFFu + ((u >> 16) & 1u)) >> 16); // RNE
}
__device__ __forceinline__ u32 pack2(float lo, float hi) {
    return (u32)f2bf(lo) | ((u32)f2bf(hi) << 16);
}
__device__ __forceinline__ float tanh_fast(float x) {
    return 1.f - 2.f / (__expf(2.f * x) + 1.f);
}
__device__ __forceinline__ short8v mk8(u32 a, u32 b, u32 c, u32 d) {
    union { u32 u[4]; short8v v; } t; t.u[0] = a; t.u[1] = b; t.u[2] = c; t.u[3] = d; return t.v;
}

// ========== proj: 4 tiles/block, B staged once, A in-register; + fused logits ==========
// Idle customer blocks (bx >= NBLK_PC) run the edge bucket histogram.
__global__ __launch_bounds__(256) void proj_both(
    const float* __restrict__ x_c, const float* __restrict__ W_c, const float* __restrict__ b_c,
    const float* __restrict__ x_p, const float* __restrict__ W_p, const float* __restrict__ b_p,
    u16* __restrict__ out_c, u16* __restrict__ out_p,
    const float* __restrict__ a_cp_s,
    const float* __restrict__ a_cp_d, const float* __restrict__ a_pp_s,
    const float* __restrict__ a_pp_d,
    float* __restrict__ al_c, float* __restrict__ al_dcp,
    float* __restrict__ al_spp, float* __restrict__ al_dpp,
    const int* __restrict__ dpp, const int* __restrict__ dcp, int* __restrict__ bcnt)
{
    __shared__ alignas(16) u16 sBT[128 * 72];    // 18432
    __shared__ alignas(16) u16 hTile[64 * 136];  // 17408
    __shared__ float aV[3][128];                 // 1536
    __shared__ int hh[NBUK];                     // 1564
    int t = threadIdx.x;
    int py = blockIdx.y;
    int bx = blockIdx.x;

    if (py == 0 && bx >= NBLK_PC) {
        int bb = bx - NBLK_PC;
        if (bb >= NBLK_E) return;
        for (int i = t; i < NBUK; i += 256) hh[i] = 0;
        __syncthreads();
        int base = bb * ECHUNK;
        int lim = min(ECHUNK, 2 * NE - base);
        for (int i = t; i < lim; i += 256) {
            int e = base + i;
            int d2 = (e < NE) ? dpp[e] : NP + dcp[e - NE];
            atomicAdd(&hh[d2 >> 10], 1);
        }
        __syncthreads();
        for (int i = t; i < NBUK; i += 256) if (hh[i]) atomicAdd(&bcnt[i], hh[i]);
        return;
    }

    const float* x; const float* W; const float* b; u16* h; int N;
    if (py == 0) { x = x_c; W = W_c; b = b_c; h = out_c; N = NC; }
    else         { x = x_p; W = W_p; b = b_p; h = out_p; N = NP; }
    if (t < 128) {
        aV[0][t] = py ? a_cp_d[t] : a_cp_s[t];
        aV[1][t] = py ? a_pp_s[t] : 0.f;
        aV[2][t] = py ? a_pp_d[t] : 0.f;
    }
    for (int i = t; i < 128 * 8; i += 256) {
        int n = i & 127, kb = i >> 7;
        u32 p[4];
#pragma unroll
        for (int j = 0; j < 4; ++j)
            p[j] = pack2(W[(kb * 8 + 2 * j) * 128 + n], W[(kb * 8 + 2 * j + 1) * 128 + n]);
        *(uint4*)(&sBT[n * 72 + kb * 8]) = make_uint4(p[0], p[1], p[2], p[3]);
    }
    __syncthreads();
    int wave = t >> 6, lane = t & 63;
    int fr = lane & 15, fq = lane >> 4;
    const u16* pB = sBT + fr * 72 + fq * 8;
    float bv8[8];
#pragma unroll
    for (int nt = 0; nt < 8; ++nt) bv8[nt] = b[nt * 16 + fr];

    for (int ti = 0; ti < 4; ++ti) {
        size_t row0 = ((size_t)bx * 4 + ti) * 64;
        if (row0 >= (size_t)N) break;
        size_t arow = row0 + wave * 16 + fr;
        short8v afr[2];
#pragma unroll
        for (int ks = 0; ks < 2; ++ks) {
            if (arow < (size_t)N) {
                const float* xp = x + arow * 64 + ks * 32 + fq * 8;
                float4 v0 = *(const float4*)xp;
                float4 v1 = *(const float4*)(xp + 4);
                afr[ks] = mk8(pack2(v0.x, v0.y), pack2(v0.z, v0.w),
                              pack2(v1.x, v1.y), pack2(v1.z, v1.w));
            } else afr[ks] = mk8(0, 0, 0, 0);
        }
        f32x4 acc[8];
#pragma unroll
        for (int nt = 0; nt < 8; ++nt) acc[nt] = (f32x4){bv8[nt], bv8[nt], bv8[nt], bv8[nt]};
#pragma unroll
        for (int ks = 0; ks < 2; ++ks) {
#pragma unroll
            for (int nt = 0; nt < 8; ++nt) {
                short8v bv = *(const short8v*)(pB + nt * 16 * 72 + ks * 32);
                acc[nt] = __builtin_amdgcn_mfma_f32_16x16x32_bf16(afr[ks], bv, acc[nt], 0, 0, 0);
            }
        }
        size_t rbase = row0 + wave * 16 + fq * 4;
        int lrow0 = wave * 16 + fq * 4;
#pragma unroll
        for (int nt = 0; nt < 8; ++nt) {
            int col = nt * 16 + fr;
#pragma unroll
            for (int rg = 0; rg < 4; ++rg) {
                size_t rr = rbase + rg;
                u16 hv = f2bf(acc[nt][rg]);
                if (rr < (size_t)N) h[rr * 128 + col] = hv;
                hTile[(lrow0 + rg) * 136 + col] = hv;
            }
        }
        __syncthreads();
        int row = t >> 2;
        size_t grow = row0 + row;
        if (grow < (size_t)N) {
#pragma unroll
            for (int hd = t & 3; hd < 8; hd += 4) {
                const u16* hp = &hTile[row * 136 + hd * 16];
                uint4 u0_ = *(const uint4*)hp;
                uint4 u1_ = *(const uint4*)(hp + 8);
                u32 uu[8] = {u0_.x, u0_.y, u0_.z, u0_.w, u1_.x, u1_.y, u1_.z, u1_.w};
                float p0 = 0.f, p1 = 0.f, p2 = 0.f;
#pragma unroll
                for (int j = 0; j < 8; ++j) {
                    float lo = bf2f((u16)(uu[j] & 0xFFFFu));
                    float hi = bf2f((u16)(uu[j] >> 16));
                    int c = hd * 16 + 2 * j;
                    p0 += lo * aV[0][c] + hi * aV[0][c + 1];
                    p1 += lo * aV[1][c] + hi * aV[1][c + 1];
                    p2 += lo * aV[2][c] + hi * aV[2][c + 1];
                }
                if (py == 0) {
                    al_c[grow * 8 + hd] = p0;
                } else {
                    al_dcp[grow * 8 + hd] = p0;
                    al_spp[grow * 8 + hd] = p1;
                    al_dpp[grow * 8 + hd] = p2;
                }
            }
        }
        __syncthreads();
    }
}

// ================= bucketed CSR build =================
__global__ __launch_bounds__(512) void bscan(const int* __restrict__ bcnt, int* __restrict__ bbase,
                                             int* __restrict__ bcur, int* __restrict__ row_ptr)
{
    __shared__ int s[512];
    int t = threadIdx.x;
    int v = (t < NBUK) ? bcnt[t] : 0;
    s[t] = v;
    __syncthreads();
    for (int off = 1; off < 512; off <<= 1) {
        int x = (t >= off) ? s[t - off] : 0;
        __syncthreads();
        s[t] += x;
        __syncthreads();
    }
    if (t < NBUK) { bbase[t] = s[t] - v; bcur[t] = s[t] - v; }
    if (t == 0) { bbase[NBUK] = 2 * NE; row_ptr[NN2] = 2 * NE; }
}

__global__ __launch_bounds__(256) void bplace(
    const int* __restrict__ spp, const int* __restrict__ dpp,
    const int* __restrict__ scp, const int* __restrict__ dcp,
    int* __restrict__ bcur, u64* __restrict__ pairs)
{
    __shared__ int h[NBUK];
    __shared__ int rk[NBUK];
    int t = threadIdx.x;
    for (int i = t; i < NBUK; i += 256) h[i] = 0;
    __syncthreads();
    int base = blockIdx.x * ECHUNK;
    int lim = min(ECHUNK, 2 * NE - base);
    for (int i = t; i < lim; i += 256) {
        int e = base + i;
        int d2 = (e < NE) ? dpp[e] : NP + dcp[e - NE];
        atomicAdd(&h[d2 >> 10], 1);
    }
    __syncthreads();
    for (int i = t; i < NBUK; i += 256) {
        int c = h[i];
        h[i] = c ? atomicAdd(&bcur[i], c) : 0;
        rk[i] = 0;
    }
    __syncthreads();
    for (int i = t; i < lim; i += 256) {
        int e = base + i;
        int d2, src;
        if (e < NE) { d2 = dpp[e];      src = spp[e]; }
        else        { d2 = NP + dcp[e - NE]; src = scp[e - NE]; }
        int b = d2 >> 10;
        int r = atomicAdd(&rk[b], 1);
        pairs[h[b] + r] = ((u64)(u32)d2 << 32) | (u32)src;
    }
}

__global__ __launch_bounds__(256) void bsort(
    const u64* __restrict__ pairs, const int* __restrict__ bbase,
    int* __restrict__ row_ptr, int* __restrict__ perm)
{
    __shared__ int cnt[1024];
    __shared__ int sc[256];
    int b = blockIdx.x, t = threadIdx.x;
    int beg = bbase[b], end = bbase[b + 1];
    for (int i = t; i < 1024; i += 256) cnt[i] = 0;
    __syncthreads();
    for (int i = beg + t; i < end; i += 256) {
        int d2 = (int)(pairs[i] >> 32);
        atomicAdd(&cnt[d2 & 1023], 1);
    }
    __syncthreads();
    int b4 = t * 4;
    int c0 = cnt[b4], c1 = cnt[b4 + 1], c2 = cnt[b4 + 2], c3 = cnt[b4 + 3];
    int s = c0 + c1 + c2 + c3;
    sc[t] = s;
    __syncthreads();
    for (int off = 1; off < 256; off <<= 1) {
        int x = (t >= off) ? sc[t - off] : 0;
        __syncthreads();
        sc[t] += x;
        __syncthreads();
    }
    int run = sc[t] - s;
    int o0 = run, o1 = run + c0, o2 = o1 + c1, o3 = o2 + c2;
    cnt[b4] = o0; cnt[b4 + 1] = o1; cnt[b4 + 2] = o2; cnt[b4 + 3] = o3;
    int gidx = b * 1024 + b4;
    if (gidx     < NN2) row_ptr[gidx]     = beg + o0;
    if (gidx + 1 < NN2) row_ptr[gidx + 1] = beg + o1;
    if (gidx + 2 < NN2) row_ptr[gidx + 2] = beg + o2;
    if (gidx + 3 < NN2) row_ptr[gidx + 3] = beg + o3;
    __syncthreads();
    for (int i = beg + t; i < end; i += 256) {
        u64 p = pairs[i];
        int d2 = (int)(p >> 32);
        int r = atomicAdd(&cnt[d2 & 1023], 1);
        perm[beg + r] = (int)(p & 0xFFFFFFFFull);
    }
}

// ===== gather (proven single-chain): 16 lanes/dst, perm preload + 1-deep pipeline =====
__global__ __launch_bounds__(256) void gather2(
    const int* __restrict__ row_ptr, const int* __restrict__ perm,
    const float* __restrict__ als_pp, const float* __restrict__ ald_pp,
    const float* __restrict__ als_cp, const float* __restrict__ ald_cp,
    const u16* __restrict__ h_p, const u16* __restrict__ h_c,
    u16* __restrict__ r_pp, u16* __restrict__ r_cp)
{
    int d2 = blockIdx.x * 16 + (threadIdx.x >> 4);
    int lane = threadIdx.x & 63;
    int l16 = lane & 15;
    int grp = lane & 48;
    int head = l16 >> 1;
    const float* als; const float* ald; const u16* hs; u16* out; int d;
    if (d2 < NP) { d = d2;      als = als_pp; ald = ald_pp; hs = h_p; out = r_pp; }
    else         { d = d2 - NP; als = als_cp; ald = ald_cp; hs = h_c; out = r_cp; }
    int beg = row_ptr[d2], end = row_ptr[d2 + 1];
    int n = end - beg;
    float ald_h = ald[(size_t)d * 8 + head];
    float dsum = 0.f;
    float acc[8] = {0.f, 0.f, 0.f, 0.f, 0.f, 0.f, 0.f, 0.f};
    for (int base = 0; base < n; base += 16) {
        int cnt = min(16, n - base);
        int my = (base + l16 < n) ? perm[beg + base + l16] : 0;
        int src = __shfl(my, grp, 64);
        float a_next = als[(size_t)src * 8 + head];
        uint4 hv_next = *(const uint4*)(hs + (size_t)src * 128 + l16 * 8);
        for (int j = 0; j < cnt; ++j) {
            float a_cur = a_next;
            uint4 hv = hv_next;
            if (j + 1 < cnt) {
                int s2 = __shfl(my, grp + j + 1, 64);
                a_next = als[(size_t)s2 * 8 + head];
                hv_next = *(const uint4*)(hs + (size_t)s2 * 128 + l16 * 8);
            }
            float a = a_cur + ald_h;
            a = a >= 0.f ? a : 0.2f * a;
            float w = __expf(a);
            dsum += w;
            u32 uu[4] = {hv.x, hv.y, hv.z, hv.w};
#pragma unroll
            for (int q = 0; q < 4; ++q) {
                acc[2 * q]     = fmaf(bf2f((u16)(uu[q] & 0xFFFFu)), w, acc[2 * q]);
                acc[2 * q + 1] = fmaf(bf2f((u16)(uu[q] >> 16)),     w, acc[2 * q + 1]);
            }
        }
    }
    float inv = 1.f / (dsum + 1e-16f);
    uint4 o;
    o.x = pack2(fmaxf(acc[0] * inv, 0.f), fmaxf(acc[1] * inv, 0.f));
    o.y = pack2(fmaxf(acc[2] * inv, 0.f), fmaxf(acc[3] * inv, 0.f));
    o.z = pack2(fmaxf(acc[4] * inv, 0.f), fmaxf(acc[5] * inv, 0.f));
    o.w = pack2(fmaxf(acc[6] * inv, 0.f), fmaxf(acc[7] * inv, 0.f));
    *(uint4*)(out + (size_t)d * 128 + l16 * 8) = o;
}

// ===== sem: B(Wk) staged once, 8 tiles/block, A direct; q-dot fused -> atomicAdd(vsum) =====
__global__ __launch_bounds__(256) void sem_mfma(
    const u16* __restrict__ r0, const u16* __restrict__ r1,
    const float* __restrict__ Wk, const float* __restrict__ bk,
    const float* __restrict__ q, float* __restrict__ vsum)
{
    __shared__ alignas(16) u16 sBT[128 * 136];
    __shared__ float red[4][128];
    __shared__ float sq_[128];
    __shared__ float dotb[128];
    int t = threadIdx.x;
    const u16* src = blockIdx.y ? r1 : r0;
    if (t < 128) sq_[t] = q[t];
    for (int i = t; i < 128 * 16; i += 256) {
        int n = i & 127, kb = i >> 7;
        u32 p[4];
#pragma unroll
        for (int j = 0; j < 4; ++j)
            p[j] = pack2(Wk[(kb * 8 + 2 * j) * 128 + n], Wk[(kb * 8 + 2 * j + 1) * 128 + n]);
        *(uint4*)(&sBT[n * 136 + kb * 8]) = make_uint4(p[0], p[1], p[2], p[3]);
    }
    __syncthreads();
    int wave = t >> 6, lane = t & 63;
    int fr = lane & 15, fq = lane >> 4;
    const u16* pB = sBT + fr * 136 + fq * 8;
    float bkv[8];
#pragma unroll
    for (int nt = 0; nt < 8; ++nt) bkv[nt] = bk[nt * 16 + fr];
    float sacc[8] = {0.f, 0.f, 0.f, 0.f, 0.f, 0.f, 0.f, 0.f};
    for (int ti = 0; ti < 8; ++ti) {
        int tile = blockIdx.x * 8 + ti;
        if (tile >= NTILE) break;
        size_t arow = (size_t)tile * 64 + wave * 16 + fr;
        const u16* ap = src + arow * 128 + fq * 8;
        short8v afr[4];
#pragma unroll
        for (int ks = 0; ks < 4; ++ks) afr[ks] = *(const short8v*)(ap + ks * 32);
        f32x4 acc[8];
#pragma unroll
        for (int nt = 0; nt < 8; ++nt) acc[nt] = (f32x4){bkv[nt], bkv[nt], bkv[nt], bkv[nt]};
#pragma unroll
        for (int ks = 0; ks < 4; ++ks) {
#pragma unroll
            for (int nt = 0; nt < 8; ++nt) {
                short8v bv = *(const short8v*)(pB + nt * 16 * 136 + ks * 32);
                acc[nt] = __builtin_amdgcn_mfma_f32_16x16x32_bf16(afr[ks], bv, acc[nt], 0, 0, 0);
            }
        }
#pragma unroll
        for (int nt = 0; nt < 8; ++nt) {
            f32x4 v = acc[nt];
            sacc[nt] += tanh_fast(v[0]) + tanh_fast(v[1]) + tanh_fast(v[2]) + tanh_fast(v[3]);
        }
    }
#pragma unroll
    for (int nt = 0; nt < 8; ++nt) {
        float s = sacc[nt];
        s += __shfl_xor(s, 16, 64);
        s += __shfl_xor(s, 32, 64);
        if (lane < 16) red[wave][nt * 16 + lane] = s;
    }
    __syncthreads();
    if (t < 128) dotb[t] = (red[0][t] + red[1][t] + red[2][t] + red[3][t]) * sq_[t];
    __syncthreads();
    if (t < 64) {
        float v = dotb[t] + dotb[t + 64];
#pragma unroll
        for (int off = 32; off >= 1; off >>= 1) v += __shfl_xor(v, off, 64);
        if (t == 0) atomicAdd(&vsum[blockIdx.y], v);
    }
}

// ==== MLP1: B(W1) staged once, 8 tiles/block, A = (a0*r_cp+a1*r_pp) in-register ====
__global__ __launch_bounds__(256) void mlp1_mfma(
    const u16* __restrict__ rcp, const u16* __restrict__ rpp, const float* __restrict__ vsum,
    const float* __restrict__ W1, const float* __restrict__ b1,
    u16* __restrict__ z1, float* __restrict__ pS, float* __restrict__ pQ)
{
    __shared__ alignas(16) u16 sBT[128 * 136];
    __shared__ float redS[4][128];
    __shared__ float redQ[4][128];
    int t = threadIdx.x;
    float v0 = vsum[0] * (1.f / (float)NP), v1 = vsum[1] * (1.f / (float)NP);
    float mx = fmaxf(v0, v1);
    float e0 = __expf(v0 - mx), e1 = __expf(v1 - mx);
    float is = 1.f / (e0 + e1);
    float a0 = e0 * is, a1 = e1 * is;
    for (int i = t; i < 128 * 16; i += 256) {
        int n = i & 127, kb = i >> 7;
        u32 p[4];
#pragma unroll
        for (int j = 0; j < 4; ++j)
            p[j] = pack2(W1[(kb * 8 + 2 * j) * 128 + n], W1[(kb * 8 + 2 * j + 1) * 128 + n]);
        *(uint4*)(&sBT[n * 136 + kb * 8]) = make_uint4(p[0], p[1], p[2], p[3]);
    }
    __syncthreads();
    int wave = t >> 6, lane = t & 63;
    int fr = lane & 15, fq = lane >> 4;
    const u16* pB = sBT + fr * 136 + fq * 8;
    float b1v[8];
#pragma unroll
    for (int nt = 0; nt < 8; ++nt) b1v[nt] = b1[nt * 16 + fr];
    float saccS[8] = {0.f, 0.f, 0.f, 0.f, 0.f, 0.f, 0.f, 0.f};
    float saccQ[8] = {0.f, 0.f, 0.f, 0.f, 0.f, 0.f, 0.f, 0.f};
    for (int ti = 0; ti < 8; ++ti) {
        int tile = blockIdx.x * 8 + ti;
        if (tile >= NTILE) break;
        size_t row0 = (size_t)tile * 64;
        size_t arow = row0 + wave * 16 + fr;
        const u16* rc = rcp + arow * 128 + fq * 8;
        const u16* rp = rpp + arow * 128 + fq * 8;
        f32x4 acc[8];
#pragma unroll
        for (int nt = 0; nt < 8; ++nt) acc[nt] = (f32x4){b1v[nt], b1v[nt], b1v[nt], b1v[nt]};
#pragma unroll
        for (int ks = 0; ks < 4; ++ks) {
            uint4 uc = *(const uint4*)(rc + ks * 32);
            uint4 up = *(const uint4*)(rp + ks * 32);
            u32 cu[4] = {uc.x, uc.y, uc.z, uc.w};
            u32 pu[4] = {up.x, up.y, up.z, up.w};
            u32 pw[4];
#pragma unroll
            for (int j = 0; j < 4; ++j) {
                float lo = a0 * bf2f((u16)(cu[j] & 0xFFFFu)) + a1 * bf2f((u16)(pu[j] & 0xFFFFu));
                float hi = a0 * bf2f((u16)(cu[j] >> 16))     + a1 * bf2f((u16)(pu[j] >> 16));
                pw[j] = pack2(lo, hi);
            }
            short8v a = mk8(pw[0], pw[1], pw[2], pw[3]);
#pragma unroll
            for (int nt = 0; nt < 8; ++nt) {
                short8v bv = *(const short8v*)(pB + nt * 16 * 136 + ks * 32);
                acc[nt] = __builtin_amdgcn_mfma_f32_16x16x32_bf16(a, bv, acc[nt], 0, 0, 0);
            }
        }
        size_t rbase = row0 + wave * 16 + fq * 4;
#pragma unroll
        for (int nt = 0; nt < 8; ++nt) {
            f32x4 v = acc[nt];
            int col = nt * 16 + fr;
#pragma unroll
            for (int rg = 0; rg < 4; ++rg)
                z1[(rbase + rg) * 128 + col] = f2bf(v[rg]);
            saccS[nt] += v[0] + v[1] + v[2] + v[3];
            saccQ[nt] += v[0] * v[0] + v[1] * v[1] + v[2] * v[2] + v[3] * v[3];
        }
    }
#pragma unroll
    for (int nt = 0; nt < 8; ++nt) {
        float s = saccS[nt], qq = saccQ[nt];
        s += __shfl_xor(s, 16, 64);  s += __shfl_xor(s, 32, 64);
        qq += __shfl_xor(qq, 16, 64); qq += __shfl_xor(qq, 32, 64);
        if (lane < 16) { redS[wave][nt * 16 + lane] = s; redQ[wave][nt * 16 + lane] = qq; }
    }
    __syncthreads();
    if (t < 128) {
        pS[(size_t)blockIdx.x * 128 + t] = redS[0][t] + redS[1][t] + redS[2][t] + redS[3][t];
        pQ[(size_t)blockIdx.x * 128 + t] = redQ[0][t] + redQ[1][t] + redQ[2][t] + redQ[3][t];
    }
}

// ================= reduce BN partials [NB8][C] -> sum/sq =================
__global__ __launch_bounds__(256) void stat_reduce(
    const float* __restrict__ pS, const float* __restrict__ pQ,
    float* __restrict__ sum, float* __restrict__ sq, int C)
{
    __shared__ float redS[256], redQ[256];
    int t = threadIdx.x;
    int c = t & (C - 1);
    int sub = t / C;
    int stride = 256 / C;
    int i0 = blockIdx.x * 25, i1 = i0 + 25;
    if (i1 > NB8) i1 = NB8;
    float s = 0.f, q = 0.f;
    for (int i = i0 + sub; i < i1; i += stride) {
        s += pS[(size_t)i * C + c];
        q += pQ[(size_t)i * C + c];
    }
    redS[t] = s; redQ[t] = q;
    __syncthreads();
    if (t < C) {
        for (int k = 1; k < stride; ++k) { s += redS[t + k * C]; q += redQ[t + k * C]; }
        atomicAdd(&sum[c], s);
        atomicAdd(&sq[c], q);
    }
}

// ===== MLP2: B(W2) staged once, 8 tiles/block, A = relu(bn(z1)) in-register =====
__global__ __launch_bounds__(256) void mlp2_mfma(
    const u16* __restrict__ z1,
    const float* __restrict__ sum1, const float* __restrict__ sq1,
    const float* __restrict__ g1, const float* __restrict__ be1,
    const float* __restrict__ W2, const float* __restrict__ b2,
    u16* __restrict__ z2, float* __restrict__ pS, float* __restrict__ pQ)
{
    __shared__ alignas(16) u16 sBT[64 * 136];
    __shared__ float sSc[128], sSh[128];
    __shared__ float redS[4][64], redQ[4][64];
    int t = threadIdx.x;
    if (t < 128) {
        float mu = sum1[t] * (1.f / (float)NP);
        float var = sq1[t] * (1.f / (float)NP) - mu * mu;
        float sc = g1[t] * rsqrtf(var + 1e-5f);
        sSc[t] = sc;
        sSh[t] = be1[t] - mu * sc;
    }
    for (int i = t; i < 64 * 16; i += 256) {
        int n = i & 63, kb = i >> 6;
        u32 p[4];
#pragma unroll
        for (int j = 0; j < 4; ++j)
            p[j] = pack2(W2[(kb * 8 + 2 * j) * 64 + n], W2[(kb * 8 + 2 * j + 1) * 64 + n]);
        *(uint4*)(&sBT[n * 136 + kb * 8]) = make_uint4(p[0], p[1], p[2], p[3]);
    }
    __syncthreads();
    int wave = t >> 6, lane = t & 63;
    int fr = lane & 15, fq = lane >> 4;
    const u16* pB = sBT + fr * 136 + fq * 8;
    float b2v[4];
#pragma unroll
    for (int nt = 0; nt < 4; ++nt) b2v[nt] = b2[nt * 16 + fr];
    float saccS[4] = {0.f, 0.f, 0.f, 0.f};
    float saccQ[4] = {0.f, 0.f, 0.f, 0.f};
    for (int ti = 0; ti < 8; ++ti) {
        int tile = blockIdx.x * 8 + ti;
        if (tile >= NTILE) break;
        size_t row0 = (size_t)tile * 64;
        size_t arow = row0 + wave * 16 + fr;
        const u16* zp = z1 + arow * 128 + fq * 8;
        f32x4 acc[4];
#pragma unroll
        for (int nt = 0; nt < 4; ++nt) acc[nt] = (f32x4){b2v[nt], b2v[nt], b2v[nt], b2v[nt]};
#pragma unroll
        for (int ks = 0; ks < 4; ++ks) {
            uint4 uz = *(const uint4*)(zp + ks * 32);
            u32 zu[4] = {uz.x, uz.y, uz.z, uz.w};
            u32 pw[4];
            int c0 = ks * 32 + fq * 8;
#pragma unroll
            for (int j = 0; j < 4; ++j) {
                int c = c0 + 2 * j;
                float lo = fmaxf(bf2f((u16)(zu[j] & 0xFFFFu)) * sSc[c] + sSh[c], 0.f);
                float hi = fmaxf(bf2f((u16)(zu[j] >> 16)) * sSc[c + 1] + sSh[c + 1], 0.f);
                pw[j] = pack2(lo, hi);
            }
            short8v a = mk8(pw[0], pw[1], pw[2], pw[3]);
#pragma unroll
            for (int nt = 0; nt < 4; ++nt) {
                short8v bv = *(const short8v*)(pB + nt * 16 * 136 + ks * 32);
                acc[nt] = __builtin_amdgcn_mfma_f32_16x16x32_bf16(a, bv, acc[nt], 0, 0, 0);
            }
        }
        size_t rbase = row0 + wave * 16 + fq * 4;
#pragma unroll
        for (int nt = 0; nt < 4; ++nt) {
            f32x4 v = acc[nt];
            int col = nt * 16 + fr;
#pragma unroll
            for (int rg = 0; rg < 4; ++rg)
                z2[(rbase + rg) * 64 + col] = f2bf(v[rg]);
            saccS[nt] += v[0] + v[1] + v[2] + v[3];
            saccQ[nt] += v[0] * v[0] + v[1] * v[1] + v[2] * v[2] + v[3] * v[3];
        }
    }
#pragma unroll
    for (int nt = 0; nt < 4; ++nt) {
        float s = saccS[nt], qq = saccQ[nt];
        s += __shfl_xor(s, 16, 64);  s += __shfl_xor(s, 32, 64);
        qq += __shfl_xor(qq, 16, 64); qq += __shfl_xor(qq, 32, 64);
        if (lane < 16) { redS[wave][nt * 16 + lane] = s; redQ[wave][nt * 16 + lane] = qq; }
    }
    __syncthreads();
    if (t < 64) {
        pS[(size_t)blockIdx.x * 64 + t] = redS[0][t] + redS[1][t] + redS[2][t] + redS[3][t];
        pQ[(size_t)blockIdx.x * 64 + t] = redQ[0][t] + redQ[1][t] + redQ[2][t] + redQ[3][t];
    }
}

// ===== final: sigmoid(relu(bn(z2)) @ W3 + b3), bf16 z2, BN computed inline =====
__global__ __launch_bounds__(64) void final_kernel(
    const u16* __restrict__ z2,
    const float* __restrict__ sum2, const float* __restrict__ sq2,
    const float* __restrict__ g2, const float* __restrict__ be2,
    const float* __restrict__ W3, const float* __restrict__ b3, float* __restrict__ out)
{
    __shared__ float sh[64][65];
    __shared__ float sw[64];
    int t = threadIdx.x; // 64
    float mu = sum2[t] * (1.f / (float)NP);
    float var = sq2[t] * (1.f / (float)NP) - mu * mu;
    float sc = g2[t] * rsqrtf(var + 1e-5f);
    float sh2 = be2[t] - mu * sc;
    size_t row0 = (size_t)blockIdx.x * 64;
    sw[t] = W3[t];
    for (int j = 0; j < 64; ++j) {
        float v = bf2f(z2[(row0 + j) * 64 + t]) * sc + sh2;
        sh[j][t] = v > 0.f ? v : 0.f;
    }
    __syncthreads();
    float acc = b3[0];
#pragma unroll 16
    for (int k = 0; k < 64; ++k) acc = fmaf(sh[t][k], sw[k], acc);
    out[row0 + t] = 1.f / (1.f + __expf(-acc));
}

extern "C" void kernel_launch(void* const* d_in, const int* in_sizes, int n_in,
                              void* d_out, int out_size, void* d_ws, size_t ws_size,
                              hipStream_t stream) {
    const float* x_c      = (const float*)d_in[0];
    const float* x_p      = (const float*)d_in[1];
    const int*   e_src_cp = (const int*)d_in[2];
    const int*   e_dst_cp = (const int*)d_in[3];
    const int*   e_src_pp = (const int*)d_in[4];
    const int*   e_dst_pp = (const int*)d_in[5];
    const float* W_c      = (const float*)d_in[6];
    const float* b_c      = (const float*)d_in[7];
    const float* W_p      = (const float*)d_in[8];
    const float* b_p      = (const float*)d_in[9];
    const float* a_src_cp = (const float*)d_in[10];
    const float* a_dst_cp = (const float*)d_in[11];
    const float* a_src_pp = (const float*)d_in[12];
    const float* a_dst_pp = (const float*)d_in[13];
    const float* Wk       = (const float*)d_in[14];
    const float* bk       = (const float*)d_in[15];
    const float* q_sem    = (const float*)d_in[16];
    const float* W1       = (const float*)d_in[17];
    const float* b1       = (const float*)d_in[18];
    const float* g1       = (const float*)d_in[19];
    const float* be1      = (const float*)d_in[20];
    const float* W2       = (const float*)d_in[21];
    const float* b2       = (const float*)d_in[22];
    const float* g2       = (const float*)d_in[23];
    const float* be2      = (const float*)d_in[24];
    const float* W3       = (const float*)d_in[25];
    const float* b3       = (const float*)d_in[26];

    // ---- byte-offset workspace layout (extent 211,208,448 B; 212,809,472 proven OK) ----
    char* ws = (char*)d_ws;
    u16*   h_p    = (u16*)  (ws +          0);  // 51,200,000
    u16*   h_c    = (u16*)  (ws +  51200000);   // 25,600,000
    float* al_c   = (float*)(ws +  76800000);   //  3,200,000
    float* al_dcp = (float*)(ws +  80000000);   //  6,400,000
    float* al_spp = (float*)(ws +  86400000);
    float* al_dpp = (float*)(ws +  92800000);
    int*   row_ptr= (int*)  (ws +  99200000);   // (NN2+1)*4 padded -> 100,800,256
    int*   perm   = (int*)  (ws + 100800256);   // 2NE*4 -> 108,800,256
    u64*   pairs  = (u64*)  (ws + 108800256);   // 2NE*8 -> 124,800,256 [dead after bsort]
    int*   bcnt   = (int*)  (ws + 124800256);   // 392*4
    int*   bbase  = (int*)  (ws + 124801856);   // 392*4
    int*   bcur   = (int*)  (ws + 124803456);   // 392*4
    u16*   r_pp   = (u16*)  (ws + 108800256);   // NP*128 bf16 (overlays pairs+bmeta, dead)
    u16*   r_cp   = (u16*)  (ws + 160000256);   // NP*128 bf16 -> 211,200,256
    float* small  = (float*)(ws + 211200256);   // 8192

    // overlays on CSR region (dead after gather2):
    float* statS  = (float*)(ws + 102400000);   // NB8*128*4 = 200,192
    float* statQ  = (float*)(ws + 104000000);   // 200,192

    float* vsum   = small;        // 2
    float* sum1   = small + 128;  // 128
    float* sq1    = small + 256;  // 128
    float* sum2   = small + 384;  // 64
    float* sq2    = small + 448;  // 64

    // aliases over dead regions
    u16*   z1 = h_p;                   // bf16 NP*128 at [0,51.2M): h_p dead after gather
    u16*   z2 = (u16*)(ws + 51200000); // bf16 NP*64 = 25.6MB at [51.2M,76.8M): h_c dead after gather

    hipMemsetAsync(small, 0, 8192, stream);
    hipMemsetAsync(bcnt, 0, 1600, stream);

    // projections (MFMA, 4 tiles/block) + fused logits; idle customer blocks run bhist
    {
        dim3 g(NBLK_PP, 2);
        proj_both<<<g, 256, 0, stream>>>(x_c, W_c, b_c, x_p, W_p, b_p, h_c, h_p,
                                         a_src_cp, a_dst_cp, a_src_pp, a_dst_pp,
                                         al_c, al_dcp, al_spp, al_dpp,
                                         e_dst_pp, e_dst_cp, bcnt);
    }

    // ---- bucketed CSR over both metapaths ----
    bscan<<<1, 512, 0, stream>>>(bcnt, bbase, bcur, row_ptr);
    bplace<<<NBLK_E, 256, 0, stream>>>(e_src_pp, e_dst_pp, e_src_cp, e_dst_cp, bcur, pairs);
    bsort<<<NBUK, 256, 0, stream>>>(pairs, bbase, row_ptr, perm);

    gather2<<<NN2 / 16, 256, 0, stream>>>(row_ptr, perm,
                                          al_spp, al_dpp, al_c, al_dcp,
                                          h_p, h_c, r_pp, r_cp);

    // semantic attention (8 tiles/block, A direct, q-dot fused)
    {
        dim3 gs(NB8, 2);
        sem_mfma<<<gs, 256, 0, stream>>>(r_cp, r_pp, Wk, bk, q_sem, vsum);
    }

    // MLP + BN (8 tiles/block, A in-register; stats via partials)
    mlp1_mfma<<<NB8, 256, 0, stream>>>(r_cp, r_pp, vsum, W1, b1, z1, statS, statQ);
    stat_reduce<<<16, 256, 0, stream>>>(statS, statQ, sum1, sq1, 128);
    mlp2_mfma<<<NB8, 256, 0, stream>>>(z1, sum1, sq1, g1, be1, W2, b2, z2, statS, statQ);
    stat_reduce<<<16, 256, 0, stream>>>(statS, statQ, sum2, sq2, 64);
    final_kernel<<<NP / 64, 64, 0, stream>>>(z2, sum2, sq2, g2, be2, W3, b3, (float*)d_out);
}